// Round 2
// 753.285 us; speedup vs baseline: 1.0100x; 1.0100x over previous
//
#include <hip/hip_runtime.h>
#include <math.h>

#define NP   100000
#define EDG  1600000
#define NK   15
#define SIGK 0.04f
#define SCH  2048
#define SNB  49            // ceil(NP/SCH)
#define MAXE 384           // max edges per 16-query block (mean 256, sigma 16)
#define AGP  968           // agg pitch in bf16 (960 + 8 pad)

typedef __bf16 v8bf __attribute__((ext_vector_type(8)));
typedef __bf16 bf4  __attribute__((ext_vector_type(4)));
typedef float  v4f  __attribute__((ext_vector_type(4)));

__device__ __forceinline__ float lk(float v) { return v >= 0.f ? v : 0.1f * v; }
__device__ __forceinline__ float bf2f(__bf16 b) { return (float)b; }

// ---------------------------------------------------------------------------
// MFMA GEMM: Out[n x Ntot] = X[n x KIN] @ W, W preshuffled bf16 B-frags.
// Block 256 thr = 4 waves; tile 128 rows x NB cols. Column stats fused.
// ---------------------------------------------------------------------------
template <int KIN, int NB, bool TRANS, bool OUTBF>
__global__ __launch_bounds__(256) void mgemm_k(const float* __restrict__ X,
                                               const __bf16* __restrict__ Wp,
                                               void* __restrict__ Out, int n, int Ntot,
                                               const float* __restrict__ ta,
                                               const float* __restrict__ tb,
                                               float* __restrict__ osum,
                                               float* __restrict__ osq) {
  constexpr int PITCH = KIN + 8;
  constexpr int NT = NB / 16;
  __shared__ __bf16 al[128 * PITCH];
  __shared__ float red[2][NB][4];
  const int tid = threadIdx.x;
  const int r0 = blockIdx.x << 7;
  const int nb0 = blockIdx.y * NB;

  constexpr int QKS = (KIN == 128) ? 5 : 4;  // log2(KIN/4)
  for (int idx = tid; idx < (128 << QKS); idx += 256) {
    const int r = idx >> QKS, q = (idx & ((1 << QKS) - 1)) << 2;
    const int row = r0 + r;
    float4 v = make_float4(0.f, 0.f, 0.f, 0.f);
    if (row < n) {
      v = *(const float4*)&X[(size_t)row * KIN + q];
      if (TRANS) {
        v.x = lk(ta[q + 0] * v.x + tb[q + 0]);
        v.y = lk(ta[q + 1] * v.y + tb[q + 1]);
        v.z = lk(ta[q + 2] * v.z + tb[q + 2]);
        v.w = lk(ta[q + 3] * v.w + tb[q + 3]);
      }
    }
    bf4 o;
    o[0] = (__bf16)v.x; o[1] = (__bf16)v.y; o[2] = (__bf16)v.z; o[3] = (__bf16)v.w;
    *(bf4*)&al[r * PITCH + q] = o;
  }
  __syncthreads();

  const int wv = tid >> 6, lane = tid & 63;
  const int mr = lane & 15, quad = lane >> 4;
  const int ntg0 = nb0 >> 4;
  const int NTG = Ntot >> 4;
  v4f acc[2][NT];
#pragma unroll
  for (int a = 0; a < 2; ++a)
#pragma unroll
    for (int b = 0; b < NT; ++b) acc[a][b] = (v4f){0.f, 0.f, 0.f, 0.f};

#pragma unroll
  for (int ks = 0; ks < KIN / 32; ++ks) {
    v8bf bf[NT];
#pragma unroll
    for (int nt = 0; nt < NT; ++nt)
      bf[nt] = ((const v8bf*)Wp)[((size_t)ks * NTG + ntg0 + nt) * 64 + lane];
#pragma unroll
    for (int mt = 0; mt < 2; ++mt) {
      const int row = (wv << 5) + (mt << 4) + mr;
      const v8bf av = *(const v8bf*)&al[row * PITCH + (ks << 5) + (quad << 3)];
#pragma unroll
      for (int nt = 0; nt < NT; ++nt)
        acc[mt][nt] = __builtin_amdgcn_mfma_f32_16x16x32_bf16(av, bf[nt], acc[mt][nt], 0, 0, 0);
    }
  }

  float csum[NT], csq[NT];
#pragma unroll
  for (int nt = 0; nt < NT; ++nt) { csum[nt] = 0.f; csq[nt] = 0.f; }
#pragma unroll
  for (int mt = 0; mt < 2; ++mt)
#pragma unroll
    for (int nt = 0; nt < NT; ++nt)
#pragma unroll
      for (int r = 0; r < 4; ++r) {
        const float v = acc[mt][nt][r];
        const int row = r0 + (wv << 5) + (mt << 4) + (quad << 2) + r;
        if (row < n) {
          const size_t o = (size_t)row * Ntot + nb0 + (nt << 4) + mr;
          if (OUTBF) ((__bf16*)Out)[o] = (__bf16)v;
          else       ((float*)Out)[o] = v;
        }
        csum[nt] += v;
        csq[nt] += v * v;
      }
#pragma unroll
  for (int nt = 0; nt < NT; ++nt) {
    float s = csum[nt], q = csq[nt];
    s += __shfl_down(s, 32); s += __shfl_down(s, 16);
    q += __shfl_down(q, 32); q += __shfl_down(q, 16);
    if (quad == 0) { red[0][(nt << 4) + mr][wv] = s; red[1][(nt << 4) + mr][wv] = q; }
  }
  __syncthreads();
  if (tid < NB) {
    const float s = red[0][tid][0] + red[0][tid][1] + red[0][tid][2] + red[0][tid][3];
    const float q = red[1][tid][0] + red[1][tid][1] + red[1][tid][2] + red[1][tid][3];
    atomicAdd(&osum[nb0 + tid], s);
    atomicAdd(&osq[nb0 + tid], q);
  }
}

// ---------------------------------------------------------------------------
__global__ void finalize_k(const float* __restrict__ sum, const float* __restrict__ sq,
                           const float* __restrict__ g, const float* __restrict__ b,
                           float* __restrict__ oa, float* __restrict__ ob, int C,
                           float invn) {
  const int c = threadIdx.x;
  if (c < C) {
    const float m = sum[c] * invn;
    const float var = sq[c] * invn - m * m;
    const float a = g[c] / sqrtf(var + 1e-5f);
    oa[c] = a;
    ob[c] = b[c] - m * a;
  }
}

// t1 bf16 -> hb bf16 with affine+leaky
__global__ __launch_bounds__(256) void normleaky_k(const __bf16* __restrict__ t,
                                                   __bf16* __restrict__ hb,
                                                   const float* __restrict__ a,
                                                   const float* __restrict__ b) {
  const int idx = (blockIdx.x << 8) + threadIdx.x;
  const int c = (idx << 2) & 63;
  const bf4 v = *(const bf4*)&t[(size_t)idx << 2];
  bf4 o;
  o[0] = (__bf16)lk(a[c + 0] * bf2f(v[0]) + b[c + 0]);
  o[1] = (__bf16)lk(a[c + 1] * bf2f(v[1]) + b[c + 1]);
  o[2] = (__bf16)lk(a[c + 2] * bf2f(v[2]) + b[c + 2]);
  o[3] = (__bf16)lk(a[c + 3] * bf2f(v[3]) + b[c + 3]);
  *(bf4*)&hb[(size_t)idx << 2] = o;
}

// out = leaky(a2*t2+b2) + asc*tsc+bsc   (t2, tsc bf16)
__global__ __launch_bounds__(256) void final_k(float* __restrict__ o,
                                               const __bf16* __restrict__ t2,
                                               const __bf16* __restrict__ tsc,
                                               const float* __restrict__ a2,
                                               const float* __restrict__ b2,
                                               const float* __restrict__ asc,
                                               const float* __restrict__ bsc) {
  const int idx = (blockIdx.x << 8) + threadIdx.x;
  const int c = (idx << 2) & 255;
  const bf4 tv = *(const bf4*)&t2[(size_t)idx << 2];
  const bf4 sv = *(const bf4*)&tsc[(size_t)idx << 2];
  float4 r;
  r.x = lk(a2[c + 0] * bf2f(tv[0]) + b2[c + 0]) + asc[c + 0] * bf2f(sv[0]) + bsc[c + 0];
  r.y = lk(a2[c + 1] * bf2f(tv[1]) + b2[c + 1]) + asc[c + 1] * bf2f(sv[1]) + bsc[c + 1];
  r.z = lk(a2[c + 2] * bf2f(tv[2]) + b2[c + 2]) + asc[c + 2] * bf2f(sv[2]) + bsc[c + 2];
  r.w = lk(a2[c + 3] * bf2f(tv[3]) + b2[c + 3]) + asc[c + 3] * bf2f(sv[3]) + bsc[c + 3];
  ((float4*)o)[idx] = r;
}

// ---------------------------------------------------------------------------
// Counting sort of edges by e_query
// ---------------------------------------------------------------------------
__global__ __launch_bounds__(256) void hist_k(const int* __restrict__ eq, int* __restrict__ cnt) {
  const int stride = gridDim.x << 8;
  for (int e = (blockIdx.x << 8) + threadIdx.x; e < EDG; e += stride)
    atomicAdd(&cnt[eq[e]], 1);
}

__global__ __launch_bounds__(256) void scanA_k(const int* __restrict__ cnt, int* __restrict__ part) {
  __shared__ int s[256];
  const int tid = threadIdx.x;
  const int base = blockIdx.x * SCH;
  int acc = 0;
  for (int i = tid; i < SCH; i += 256) {
    const int idx = base + i;
    if (idx < NP) acc += cnt[idx];
  }
  s[tid] = acc;
  __syncthreads();
  for (int d = 128; d > 0; d >>= 1) {
    if (tid < d) s[tid] += s[tid + d];
    __syncthreads();
  }
  if (tid == 0) part[blockIdx.x] = s[0];
}

__global__ void scanB_k(int* __restrict__ part, int* __restrict__ off) {
  if (threadIdx.x == 0) {
    int run = 0;
    for (int i = 0; i < SNB; ++i) { const int v = part[i]; part[i] = run; run += v; }
    off[NP] = EDG;
  }
}

__global__ __launch_bounds__(256) void scanC_k(const int* __restrict__ cnt,
                                               const int* __restrict__ part,
                                               int* __restrict__ off, int* __restrict__ cur) {
  __shared__ int s[256];
  const int tid = threadIdx.x;
  const int base = blockIdx.x * SCH + tid * 8;
  int loc[8];
  int mysum = 0;
#pragma unroll
  for (int j = 0; j < 8; ++j) {
    const int idx = base + j;
    const int v = (idx < NP) ? cnt[idx] : 0;
    loc[j] = mysum;
    mysum += v;
  }
  s[tid] = mysum;
  __syncthreads();
  for (int d = 1; d < 256; d <<= 1) {
    int v = (tid >= d) ? s[tid - d] : 0;
    __syncthreads();
    s[tid] += v;
    __syncthreads();
  }
  const int tb = part[blockIdx.x] + s[tid] - mysum;
#pragma unroll
  for (int j = 0; j < 8; ++j) {
    const int idx = base + j;
    if (idx < NP) { off[idx] = tb + loc[j]; cur[idx] = tb + loc[j]; }
  }
}

__global__ __launch_bounds__(256) void scat_k(const int* __restrict__ er,
                                              const int* __restrict__ eq,
                                              int* __restrict__ cur, int* __restrict__ sref) {
  const int stride = gridDim.x << 8;
  for (int e = (blockIdx.x << 8) + threadIdx.x; e < EDG; e += stride) {
    const int p = atomicAdd(&cur[eq[e]], 1);
    sref[p] = er[e];
  }
}

// ---------------------------------------------------------------------------
// One-shot preshuffle of all weights into bf16 MFMA B-frag layouts.
// ---------------------------------------------------------------------------
__device__ __forceinline__ void wshuf1(const float* W, __bf16* Wp, int idx, int Ntot) {
  const int j = idx & 7;
  const int lane = (idx >> 3) & 63;
  const int rest = idx >> 9;
  const int NTG = Ntot >> 4;
  const int ntg = rest % NTG;
  const int ks = rest / NTG;
  Wp[idx] = (__bf16)W[(size_t)(ks * 32 + ((lane >> 4) << 3) + j) * Ntot + ntg * 16 + (lane & 15)];
}

__global__ __launch_bounds__(256) void allshuf_k(const float* __restrict__ W1,
                                                 const float* __restrict__ Wsc,
                                                 const float* __restrict__ W2,
                                                 const float* __restrict__ Wkp,
                                                 __bf16* __restrict__ base) {
  const int i = (blockIdx.x << 8) + threadIdx.x;
  if (i < 8192) {
    wshuf1(W1, base, i, 64);
  } else if (i < 40960) {
    wshuf1(Wsc, base + 8192, i - 8192, 256);
  } else if (i < 57344) {
    wshuf1(W2, base + 40960, i - 40960, 256);
  } else if (i < 118784) {
    const int idx = i - 57344;
    const int j = idx & 7;
    const int lane = (idx >> 3) & 63;
    const int nt = (idx >> 9) & 3;
    const int kb = (idx >> 11) & 1;
    const int k = idx >> 12;
    const int kd = kb * 32 + ((lane >> 4) << 3) + j;
    const int n = nt * 16 + (lane & 15);
    (base + 57344)[idx] = (__bf16)Wkp[(k * 64 + kd) * 64 + n];
  }
}

// ---------------------------------------------------------------------------
// KPConv gather: block = 16 queries (256 thr).
// Stage 1 (edge-parallel): refs + fp32 influences (zeros where inactive) -> LDS
//   via float4 stores (the 16 scalar stores were a 32-way bank conflict).
// Stage 2: lane owns (query, 4-ch chunk) EXCLUSIVELY; register accumulators
//   acc[15][4]; per edge: broadcast LDS reads of infl + 2-deep-prefetched bf16
//   h gather (ref index read 3-ahead so the refsL LDS latency doesn't eat the
//   global prefetch distance); 60 unconditional v_fma.
// LDS: inflF+refsL are fully consumed before aggL is first written, so they
//   share one union region (barrier between last read and first write).
//   31.3 KB total -> 4 blocks/CU (VGPR-capped 16 waves/CU) vs 57.8 KB/2 blocks
//   before: the kernel was latency-bound at 20% occupancy.
// Phase B: y[16x64] = sum_k agg @ W_k via MFMA; column stats fused (atomics).
// ---------------------------------------------------------------------------
__global__ __launch_bounds__(256, 4) void kpagg_k(const float* __restrict__ pos,
                                                  const int* __restrict__ sref,
                                                  const int* __restrict__ off,
                                                  const float* __restrict__ kpts,
                                                  const __bf16* __restrict__ Wf,
                                                  const __bf16* __restrict__ hb,
                                                  float* __restrict__ y,
                                                  float* __restrict__ osum,
                                                  float* __restrict__ osq) {
  constexpr int INFL_BYTES = MAXE * 16 * 4;     // 24,576
  constexpr int UNION_BYTES = 16 * AGP * 2;     // 30,976 > 24,576 + 1,536
  __shared__ __align__(16) char uSm[UNION_BYTES];
  __shared__ int qoffL[17];
  __shared__ float kpL[48];
  float* inflF = (float*)uSm;                   // [MAXE][16], k=15 zeroed
  int* refsL = (int*)(uSm + INFL_BYTES);        // [MAXE]
  __bf16* aggL = (__bf16*)uSm;                  // [16][AGP] (overlays the above)

  const int tid = threadIdx.x;
  const int q0 = blockIdx.x << 4;
  if (tid < 17) qoffL[tid] = off[q0 + tid];
  if (tid >= 32 && tid < 32 + 45) kpL[tid - 32] = kpts[tid - 32];
  __syncthreads();

  const int e0 = qoffL[0];
  int nE = qoffL[16] - e0;
  if (nE > MAXE) nE = MAXE;
  if (nE == 0 && tid == 0) refsL[0] = 0;        // keep prologue gather in-bounds

  // ---- stage 1: edge-parallel influence compute ----
  for (int i = tid; i < nE; i += 256) {
    const int e = e0 + i;
    const int ref = sref[e];
    refsL[i] = ref;
    int lo = 0, hi = 16;
    while (hi - lo > 1) { const int mid = (lo + hi) >> 1; if (qoffL[mid] <= e) lo = mid; else hi = mid; }
    const int q = q0 + lo;
    const float4 pr = *(const float4*)&pos[ref * 4];
    const float4 pq = *(const float4*)&pos[q * 4];
    const float rx = pr.y - pq.y, ry = pr.z - pq.z, rz = pr.w - pq.w;
    float wk[16];
#pragma unroll
    for (int k = 0; k < NK; ++k) {
      const float dx = rx - kpL[k * 3 + 0];
      const float dy = ry - kpL[k * 3 + 1];
      const float dz = rz - kpL[k * 3 + 2];
      const float w = 1.f - sqrtf(dx * dx + dy * dy + dz * dz) * (1.f / SIGK);
      wk[k] = w > 0.f ? w : 0.f;
    }
    wk[15] = 0.f;
    *(float4*)&inflF[i * 16 + 0]  = make_float4(wk[0], wk[1], wk[2], wk[3]);
    *(float4*)&inflF[i * 16 + 4]  = make_float4(wk[4], wk[5], wk[6], wk[7]);
    *(float4*)&inflF[i * 16 + 8]  = make_float4(wk[8], wk[9], wk[10], wk[11]);
    *(float4*)&inflF[i * 16 + 12] = make_float4(wk[12], wk[13], wk[14], wk[15]);
  }
  __syncthreads();

  // ---- stage 2: register accumulation ----
  const int wv = tid >> 6, lane = tid & 63;
  const int ql = (wv << 2) + (lane >> 4);   // query owned by this lane
  const int t4 = (lane & 15) << 2;          // channel chunk
  const int le0 = qoffL[ql] - e0;
  int le1 = qoffL[ql + 1] - e0;
  if (le1 > nE) le1 = nE;
  const int len = le1 - le0;

  float acc[NK][4];
#pragma unroll
  for (int k = 0; k < NK; ++k) { acc[k][0] = acc[k][1] = acc[k][2] = acc[k][3] = 0.f; }

  // 2-deep h prefetch; ref index read one more iteration ahead.
  const int j0 = (len > 0) ? le0 : 0;
  const int j1 = (len > 1) ? le0 + 1 : j0;
  const int j2 = (len > 2) ? le0 + 2 : j1;
  bf4 hA = *(const bf4*)&hb[(size_t)refsL[j0] * 64 + t4];
  bf4 hB = *(const bf4*)&hb[(size_t)refsL[j1] * 64 + t4];
  int refC = refsL[j2];
#pragma unroll 1
  for (int j = le0; j < le1; ++j) {
    const bf4 hv = hA;
    hA = hB;
    hB = *(const bf4*)&hb[(size_t)refC * 64 + t4];   // prefetch j+2
    const int jn = (j + 3 < le1) ? j + 3 : le1 - 1;
    refC = refsL[jn];                                 // ref for j+3
    const float f0 = bf2f(hv[0]), f1 = bf2f(hv[1]), f2 = bf2f(hv[2]), f3 = bf2f(hv[3]);
    const float4 wA = *(const float4*)&inflF[j * 16 + 0];
    const float4 wB = *(const float4*)&inflF[j * 16 + 4];
    const float4 wC = *(const float4*)&inflF[j * 16 + 8];
    const float4 wD = *(const float4*)&inflF[j * 16 + 12];
    const float wk[NK] = {wA.x, wA.y, wA.z, wA.w, wB.x, wB.y, wB.z, wB.w,
                          wC.x, wC.y, wC.z, wC.w, wD.x, wD.y, wD.z};
#pragma unroll
    for (int k = 0; k < NK; ++k) {
      acc[k][0] += wk[k] * f0;
      acc[k][1] += wk[k] * f1;
      acc[k][2] += wk[k] * f2;
      acc[k][3] += wk[k] * f3;
    }
  }

  // inflF/refsL fully consumed by every wave before aggL overwrites the union
  __syncthreads();

  // write agg (bf16) for phase B
#pragma unroll
  for (int k = 0; k < NK; ++k) {
    bf4 o;
    o[0] = (__bf16)acc[k][0]; o[1] = (__bf16)acc[k][1];
    o[2] = (__bf16)acc[k][2]; o[3] = (__bf16)acc[k][3];
    *(bf4*)&aggL[ql * AGP + k * 64 + t4] = o;
  }
  __syncthreads();

  // ---- phase B: MFMA y = agg @ Wk, wave wv -> cols [wv*16, wv*16+16) ----
  const int m = lane & 15, quad = lane >> 4;
  v4f yacc = {0.f, 0.f, 0.f, 0.f};
  const v8bf* Wf8 = (const v8bf*)Wf;
#pragma unroll
  for (int k = 0; k < NK; ++k)
#pragma unroll
    for (int kb = 0; kb < 2; ++kb) {
      const v8bf av = *(const v8bf*)&aggL[m * AGP + k * 64 + kb * 32 + (quad << 3)];
      const v8bf bv = Wf8[((k * 2 + kb) * 4 + wv) * 64 + lane];
      yacc = __builtin_amdgcn_mfma_f32_16x16x32_bf16(av, bv, yacc, 0, 0, 0);
    }

  float s = 0.f, q2 = 0.f;
#pragma unroll
  for (int r = 0; r < 4; ++r) {
    const float v = yacc[r];
    y[(size_t)(q0 + (quad << 2) + r) * 64 + (wv << 4) + m] = v;
    s += v; q2 += v * v;
  }
  s += __shfl_down(s, 32); s += __shfl_down(s, 16);
  q2 += __shfl_down(q2, 32); q2 += __shfl_down(q2, 16);
  if (quad == 0) {
    atomicAdd(&osum[(wv << 4) + m], s);
    atomicAdd(&osq[(wv << 4) + m], q2);
  }
}

// ---------------------------------------------------------------------------
extern "C" void kernel_launch(void* const* d_in, const int* in_sizes, int n_in,
                              void* d_out, int out_size, void* d_ws, size_t ws_size,
                              hipStream_t stream) {
  const float* pos = (const float*)d_in[0];
  const float* x   = (const float*)d_in[1];
  const int* er    = (const int*)d_in[2];
  const int* eq    = (const int*)d_in[3];
  const float* W1  = (const float*)d_in[4];
  const float* g1  = (const float*)d_in[5];
  const float* b1  = (const float*)d_in[6];
  const float* kp  = (const float*)d_in[7];
  const float* Wkp = (const float*)d_in[8];
  const float* gkp = (const float*)d_in[9];
  const float* bkp = (const float*)d_in[10];
  const float* W2  = (const float*)d_in[11];
  const float* g2  = (const float*)d_in[12];
  const float* b2  = (const float*)d_in[13];
  const float* Wsc = (const float*)d_in[14];
  const float* gsc = (const float*)d_in[15];
  const float* bsc = (const float*)d_in[16];
  float* out = (float*)d_out;
  float* ws = (float*)d_ws;

  // stats / affine scratch (first 4096 floats)
  float* sum1 = ws;          float* sq1  = ws + 64;
  float* sumsc = ws + 128;   float* sqsc = ws + 384;
  float* sumy = ws + 640;    float* sqy  = ws + 704;
  float* sum2 = ws + 768;    float* sq2  = ws + 1024;
  float* a1v = ws + 1280;    float* b1v  = ws + 1344;
  float* ascv = ws + 1408;   float* bscv = ws + 1664;
  float* ayv = ws + 1920;    float* byv  = ws + 1984;
  float* a2v = ws + 2048;    float* b2v  = ws + 2304;

  // layout (float offsets)
  __bf16* Wpb = (__bf16*)(ws + 4096);            // preshuffled weights
  __bf16* W1p = Wpb;
  __bf16* Wscp = Wpb + 8192;
  __bf16* W2p = Wpb + 40960;
  __bf16* Wfp = Wpb + 57344;
  __bf16* hb = (__bf16*)(ws + 69632);            // bf16 [N*64]
  float* ybuf = ws + 69632 + 3200000;            // fp32 [N*64]
  float* t1bf = ybuf + 6400000;                  // bf16 t1 [N*64] region
  __bf16* t1b = (__bf16*)t1bf;
  __bf16* tscb = (__bf16*)ybuf;                  // bf16 [N*256] overlays ybuf+t1b
  int* cnt = (int*)(t1bf + 6400000);             // sort region
  int* off = cnt + 100352;
  int* cur = off + 100352;
  int* part = cur + 100352;
  int* sref = part + 256;
  __bf16* t2b = (__bf16*)cnt;                    // bf16 [N*256] overlays sort region

  const float invn = 1.f / (float)NP;

  (void)hipMemsetAsync(ws, 0, 4096 * sizeof(float), stream);
  (void)hipMemsetAsync(cnt, 0, 100352 * sizeof(int), stream);

  // weight preshuffle
  allshuf_k<<<464, 256, 0, stream>>>(W1, Wsc, W2, Wkp, Wpb);

  // unary_1: t1b = bf16(x@W1) (stats fused) ; fold ; hb = bf16(leaky(BN))
  mgemm_k<128, 64, false, true><<<dim3(782, 1), 256, 0, stream>>>(
      x, W1p, t1b, NP, 64, nullptr, nullptr, sum1, sq1);
  finalize_k<<<1, 256, 0, stream>>>(sum1, sq1, g1, b1, a1v, b1v, 64, invn);
  normleaky_k<<<6250, 256, 0, stream>>>(t1b, hb, a1v, b1v);

  // edge sort by query
  hist_k<<<2048, 256, 0, stream>>>(eq, cnt);
  scanA_k<<<SNB, 256, 0, stream>>>(cnt, part);
  scanB_k<<<1, 64, 0, stream>>>(part, off);
  scanC_k<<<SNB, 256, 0, stream>>>(cnt, part, off, cur);
  scat_k<<<2048, 256, 0, stream>>>(er, eq, cur, sref);

  // KPConv (y stats fused)
  kpagg_k<<<6250, 256, 0, stream>>>(pos, sref, off, kp, Wfp, hb, ybuf, sumy, sqy);
  finalize_k<<<1, 256, 0, stream>>>(sumy, sqy, gkp, bkp, ayv, byv, 64, invn);

  // unary_2: t2b = bf16( leaky(BN(y)) @ W2 ), stats fused (overwrites sort bufs)
  mgemm_k<64, 128, true, true><<<dim3(782, 2), 256, 0, stream>>>(
      ybuf, W2p, t2b, NP, 256, ayv, byv, sum2, sq2);
  finalize_k<<<1, 256, 0, stream>>>(sum2, sq2, g2, b2, a2v, b2v, 256, invn);

  // shortcut: tscb = bf16( x@Wsc ), stats fused (overwrites ybuf/t1b)
  mgemm_k<128, 128, false, true><<<dim3(782, 2), 256, 0, stream>>>(
      x, Wscp, tscb, NP, 256, nullptr, nullptr, sumsc, sqsc);
  finalize_k<<<1, 256, 0, stream>>>(sumsc, sqsc, gsc, bsc, ascv, bscv, 256, invn);

  // out = leaky(BN(t2)) + BN(tsc)
  final_k<<<25000, 256, 0, stream>>>(out, t2b, tscb, a2v, b2v, ascv, bscv);
}

// Round 3
// 740.509 us; speedup vs baseline: 1.0274x; 1.0173x over previous
//
#include <hip/hip_runtime.h>
#include <math.h>

#define NP   100000
#define EDG  1600000
#define NK   15
#define SIGK 0.04f
#define SCH  2048
#define SNB  49            // ceil(NP/SCH)
#define MAXE 384           // max edges per 16-query block (mean 256, sigma 16)
#define AGP  968           // agg pitch in bf16 (960 + 8 pad)

typedef __bf16 v8bf __attribute__((ext_vector_type(8)));
typedef __bf16 bf4  __attribute__((ext_vector_type(4)));
typedef float  v4f  __attribute__((ext_vector_type(4)));

__device__ __forceinline__ float lk(float v) { return v >= 0.f ? v : 0.1f * v; }
__device__ __forceinline__ float bf2f(__bf16 b) { return (float)b; }

// ---------------------------------------------------------------------------
// MFMA GEMM: Out[n x Ntot] = X[n x KIN] @ W, W preshuffled bf16 B-frags.
// Block 256 thr = 4 waves; tile 128 rows x NB cols. Column stats fused.
// ---------------------------------------------------------------------------
template <int KIN, int NB, bool TRANS, bool OUTBF>
__global__ __launch_bounds__(256) void mgemm_k(const float* __restrict__ X,
                                               const __bf16* __restrict__ Wp,
                                               void* __restrict__ Out, int n, int Ntot,
                                               const float* __restrict__ ta,
                                               const float* __restrict__ tb,
                                               float* __restrict__ osum,
                                               float* __restrict__ osq) {
  constexpr int PITCH = KIN + 8;
  constexpr int NT = NB / 16;
  __shared__ __bf16 al[128 * PITCH];
  __shared__ float red[2][NB][4];
  const int tid = threadIdx.x;
  const int r0 = blockIdx.x << 7;
  const int nb0 = blockIdx.y * NB;

  constexpr int QKS = (KIN == 128) ? 5 : 4;  // log2(KIN/4)
  for (int idx = tid; idx < (128 << QKS); idx += 256) {
    const int r = idx >> QKS, q = (idx & ((1 << QKS) - 1)) << 2;
    const int row = r0 + r;
    float4 v = make_float4(0.f, 0.f, 0.f, 0.f);
    if (row < n) {
      v = *(const float4*)&X[(size_t)row * KIN + q];
      if (TRANS) {
        v.x = lk(ta[q + 0] * v.x + tb[q + 0]);
        v.y = lk(ta[q + 1] * v.y + tb[q + 1]);
        v.z = lk(ta[q + 2] * v.z + tb[q + 2]);
        v.w = lk(ta[q + 3] * v.w + tb[q + 3]);
      }
    }
    bf4 o;
    o[0] = (__bf16)v.x; o[1] = (__bf16)v.y; o[2] = (__bf16)v.z; o[3] = (__bf16)v.w;
    *(bf4*)&al[r * PITCH + q] = o;
  }
  __syncthreads();

  const int wv = tid >> 6, lane = tid & 63;
  const int mr = lane & 15, quad = lane >> 4;
  const int ntg0 = nb0 >> 4;
  const int NTG = Ntot >> 4;
  v4f acc[2][NT];
#pragma unroll
  for (int a = 0; a < 2; ++a)
#pragma unroll
    for (int b = 0; b < NT; ++b) acc[a][b] = (v4f){0.f, 0.f, 0.f, 0.f};

#pragma unroll
  for (int ks = 0; ks < KIN / 32; ++ks) {
    v8bf bf[NT];
#pragma unroll
    for (int nt = 0; nt < NT; ++nt)
      bf[nt] = ((const v8bf*)Wp)[((size_t)ks * NTG + ntg0 + nt) * 64 + lane];
#pragma unroll
    for (int mt = 0; mt < 2; ++mt) {
      const int row = (wv << 5) + (mt << 4) + mr;
      const v8bf av = *(const v8bf*)&al[row * PITCH + (ks << 5) + (quad << 3)];
#pragma unroll
      for (int nt = 0; nt < NT; ++nt)
        acc[mt][nt] = __builtin_amdgcn_mfma_f32_16x16x32_bf16(av, bf[nt], acc[mt][nt], 0, 0, 0);
    }
  }

  float csum[NT], csq[NT];
#pragma unroll
  for (int nt = 0; nt < NT; ++nt) { csum[nt] = 0.f; csq[nt] = 0.f; }
#pragma unroll
  for (int mt = 0; mt < 2; ++mt)
#pragma unroll
    for (int nt = 0; nt < NT; ++nt)
#pragma unroll
      for (int r = 0; r < 4; ++r) {
        const float v = acc[mt][nt][r];
        const int row = r0 + (wv << 5) + (mt << 4) + (quad << 2) + r;
        if (row < n) {
          const size_t o = (size_t)row * Ntot + nb0 + (nt << 4) + mr;
          if (OUTBF) ((__bf16*)Out)[o] = (__bf16)v;
          else       ((float*)Out)[o] = v;
        }
        csum[nt] += v;
        csq[nt] += v * v;
      }
#pragma unroll
  for (int nt = 0; nt < NT; ++nt) {
    float s = csum[nt], q = csq[nt];
    s += __shfl_down(s, 32); s += __shfl_down(s, 16);
    q += __shfl_down(q, 32); q += __shfl_down(q, 16);
    if (quad == 0) { red[0][(nt << 4) + mr][wv] = s; red[1][(nt << 4) + mr][wv] = q; }
  }
  __syncthreads();
  if (tid < NB) {
    const float s = red[0][tid][0] + red[0][tid][1] + red[0][tid][2] + red[0][tid][3];
    const float q = red[1][tid][0] + red[1][tid][1] + red[1][tid][2] + red[1][tid][3];
    atomicAdd(&osum[nb0 + tid], s);
    atomicAdd(&osq[nb0 + tid], q);
  }
}

// ---------------------------------------------------------------------------
__global__ void finalize_k(const float* __restrict__ sum, const float* __restrict__ sq,
                           const float* __restrict__ g, const float* __restrict__ b,
                           float* __restrict__ oa, float* __restrict__ ob, int C,
                           float invn) {
  const int c = threadIdx.x;
  if (c < C) {
    const float m = sum[c] * invn;
    const float var = sq[c] * invn - m * m;
    const float a = g[c] / sqrtf(var + 1e-5f);
    oa[c] = a;
    ob[c] = b[c] - m * a;
  }
}

// t1 bf16 -> hb bf16 with affine+leaky
__global__ __launch_bounds__(256) void normleaky_k(const __bf16* __restrict__ t,
                                                   __bf16* __restrict__ hb,
                                                   const float* __restrict__ a,
                                                   const float* __restrict__ b) {
  const int idx = (blockIdx.x << 8) + threadIdx.x;
  const int c = (idx << 2) & 63;
  const bf4 v = *(const bf4*)&t[(size_t)idx << 2];
  bf4 o;
  o[0] = (__bf16)lk(a[c + 0] * bf2f(v[0]) + b[c + 0]);
  o[1] = (__bf16)lk(a[c + 1] * bf2f(v[1]) + b[c + 1]);
  o[2] = (__bf16)lk(a[c + 2] * bf2f(v[2]) + b[c + 2]);
  o[3] = (__bf16)lk(a[c + 3] * bf2f(v[3]) + b[c + 3]);
  *(bf4*)&hb[(size_t)idx << 2] = o;
}

// out = leaky(a2*t2+b2) + asc*tsc+bsc   (t2, tsc bf16)
__global__ __launch_bounds__(256) void final_k(float* __restrict__ o,
                                               const __bf16* __restrict__ t2,
                                               const __bf16* __restrict__ tsc,
                                               const float* __restrict__ a2,
                                               const float* __restrict__ b2,
                                               const float* __restrict__ asc,
                                               const float* __restrict__ bsc) {
  const int idx = (blockIdx.x << 8) + threadIdx.x;
  const int c = (idx << 2) & 255;
  const bf4 tv = *(const bf4*)&t2[(size_t)idx << 2];
  const bf4 sv = *(const bf4*)&tsc[(size_t)idx << 2];
  float4 r;
  r.x = lk(a2[c + 0] * bf2f(tv[0]) + b2[c + 0]) + asc[c + 0] * bf2f(sv[0]) + bsc[c + 0];
  r.y = lk(a2[c + 1] * bf2f(tv[1]) + b2[c + 1]) + asc[c + 1] * bf2f(sv[1]) + bsc[c + 1];
  r.z = lk(a2[c + 2] * bf2f(tv[2]) + b2[c + 2]) + asc[c + 2] * bf2f(sv[2]) + bsc[c + 2];
  r.w = lk(a2[c + 3] * bf2f(tv[3]) + b2[c + 3]) + asc[c + 3] * bf2f(sv[3]) + bsc[c + 3];
  ((float4*)o)[idx] = r;
}

// ---------------------------------------------------------------------------
// Counting sort of edges by e_query
// ---------------------------------------------------------------------------
__global__ __launch_bounds__(256) void hist_k(const int* __restrict__ eq, int* __restrict__ cnt) {
  const int stride = gridDim.x << 8;
  for (int e = (blockIdx.x << 8) + threadIdx.x; e < EDG; e += stride)
    atomicAdd(&cnt[eq[e]], 1);
}

__global__ __launch_bounds__(256) void scanA_k(const int* __restrict__ cnt, int* __restrict__ part) {
  __shared__ int s[256];
  const int tid = threadIdx.x;
  const int base = blockIdx.x * SCH;
  int acc = 0;
  for (int i = tid; i < SCH; i += 256) {
    const int idx = base + i;
    if (idx < NP) acc += cnt[idx];
  }
  s[tid] = acc;
  __syncthreads();
  for (int d = 128; d > 0; d >>= 1) {
    if (tid < d) s[tid] += s[tid + d];
    __syncthreads();
  }
  if (tid == 0) part[blockIdx.x] = s[0];
}

__global__ void scanB_k(int* __restrict__ part, int* __restrict__ off) {
  if (threadIdx.x == 0) {
    int run = 0;
    for (int i = 0; i < SNB; ++i) { const int v = part[i]; part[i] = run; run += v; }
    off[NP] = EDG;
  }
}

__global__ __launch_bounds__(256) void scanC_k(const int* __restrict__ cnt,
                                               const int* __restrict__ part,
                                               int* __restrict__ off, int* __restrict__ cur) {
  __shared__ int s[256];
  const int tid = threadIdx.x;
  const int base = blockIdx.x * SCH + tid * 8;
  int loc[8];
  int mysum = 0;
#pragma unroll
  for (int j = 0; j < 8; ++j) {
    const int idx = base + j;
    const int v = (idx < NP) ? cnt[idx] : 0;
    loc[j] = mysum;
    mysum += v;
  }
  s[tid] = mysum;
  __syncthreads();
  for (int d = 1; d < 256; d <<= 1) {
    int v = (tid >= d) ? s[tid - d] : 0;
    __syncthreads();
    s[tid] += v;
    __syncthreads();
  }
  const int tb = part[blockIdx.x] + s[tid] - mysum;
#pragma unroll
  for (int j = 0; j < 8; ++j) {
    const int idx = base + j;
    if (idx < NP) { off[idx] = tb + loc[j]; cur[idx] = tb + loc[j]; }
  }
}

__global__ __launch_bounds__(256) void scat_k(const int* __restrict__ er,
                                              const int* __restrict__ eq,
                                              int* __restrict__ cur, int* __restrict__ sref) {
  const int stride = gridDim.x << 8;
  for (int e = (blockIdx.x << 8) + threadIdx.x; e < EDG; e += stride) {
    const int p = atomicAdd(&cur[eq[e]], 1);
    sref[p] = er[e];
  }
}

// ---------------------------------------------------------------------------
// One-shot preshuffle of all weights into bf16 MFMA B-frag layouts.
// ---------------------------------------------------------------------------
__device__ __forceinline__ void wshuf1(const float* W, __bf16* Wp, int idx, int Ntot) {
  const int j = idx & 7;
  const int lane = (idx >> 3) & 63;
  const int rest = idx >> 9;
  const int NTG = Ntot >> 4;
  const int ntg = rest % NTG;
  const int ks = rest / NTG;
  Wp[idx] = (__bf16)W[(size_t)(ks * 32 + ((lane >> 4) << 3) + j) * Ntot + ntg * 16 + (lane & 15)];
}

__global__ __launch_bounds__(256) void allshuf_k(const float* __restrict__ W1,
                                                 const float* __restrict__ Wsc,
                                                 const float* __restrict__ W2,
                                                 const float* __restrict__ Wkp,
                                                 __bf16* __restrict__ base) {
  const int i = (blockIdx.x << 8) + threadIdx.x;
  if (i < 8192) {
    wshuf1(W1, base, i, 64);
  } else if (i < 40960) {
    wshuf1(Wsc, base + 8192, i - 8192, 256);
  } else if (i < 57344) {
    wshuf1(W2, base + 40960, i - 40960, 256);
  } else if (i < 118784) {
    const int idx = i - 57344;
    const int j = idx & 7;
    const int lane = (idx >> 3) & 63;
    const int nt = (idx >> 9) & 3;
    const int kb = (idx >> 11) & 1;
    const int k = idx >> 12;
    const int kd = kb * 32 + ((lane >> 4) << 3) + j;
    const int n = nt * 16 + (lane & 15);
    (base + 57344)[idx] = (__bf16)Wkp[(k * 64 + kd) * 64 + n];
  }
}

// ---------------------------------------------------------------------------
// Per-edge influence helper: fills w[0..15] (w[15]=0 pad), returns true if any
// kernel point is active for this edge.
// ---------------------------------------------------------------------------
__device__ __forceinline__ bool kp_infl(const float* __restrict__ pos,
                                        const int* __restrict__ sref,
                                        const int* qoffL, const float* kpL,
                                        int e, int q0, int& ref, int& lo, float* w) {
  ref = sref[e];
  int l = 0, h = 16;
  while (h - l > 1) { const int mid = (l + h) >> 1; if (qoffL[mid] <= e) l = mid; else h = mid; }
  lo = l;
  const float4 pr = *(const float4*)&pos[ref * 4];
  const float4 pq = *(const float4*)&pos[(q0 + l) * 4];
  const float rx = pr.y - pq.y, ry = pr.z - pq.z, rz = pr.w - pq.w;
  bool act = false;
#pragma unroll
  for (int k = 0; k < NK; ++k) {
    const float dx = rx - kpL[k * 3 + 0];
    const float dy = ry - kpL[k * 3 + 1];
    const float dz = rz - kpL[k * 3 + 2];
    const float v = 1.f - sqrtf(dx * dx + dy * dy + dz * dz) * (1.f / SIGK);
    const float wv = v > 0.f ? v : 0.f;
    w[k] = wv;
    act = act || (wv > 0.f);
  }
  w[15] = 0.f;
  return act;
}

// ---------------------------------------------------------------------------
// KPConv gather: block = 16 queries (256 thr).
// ACTIVE-EDGE COMPACTION: with uniform pos in a 0.1 box and sigma=0.04, only
//   ~10-20% of edges have ANY active kernel point; the rest contribute exactly
//   zero. Pass A (edge-parallel) computes influences into registers and counts
//   actives per query (LDS atomic rank; within-query order is already
//   nondeterministic from scat_k, so no new numeric risk). Tiny 16-way scan ->
//   compact offsets qA. Pass B scatters only active edges' refs + influence
//   rows. Stage 2 then loops over ~2-4 active edges/lane instead of ~16,
//   skipping the dead hb gathers entirely.
// Stage 2: lane owns (query, 4-ch chunk); register acc[15][4]; per active edge
//   broadcast LDS influence reads + 2-deep prefetched bf16 h gather; 60 v_fma.
// LDS union (31.3 KB total -> 4 blocks/CU): inflF/refsL consumed before aggL
//   overwrites them (barrier between).
// Phase B: y[16x64] = sum_k agg @ W_k via MFMA; column stats fused (atomics).
// ---------------------------------------------------------------------------
__global__ __launch_bounds__(256, 4) void kpagg_k(const float* __restrict__ pos,
                                                  const int* __restrict__ sref,
                                                  const int* __restrict__ off,
                                                  const float* __restrict__ kpts,
                                                  const __bf16* __restrict__ Wf,
                                                  const __bf16* __restrict__ hb,
                                                  float* __restrict__ y,
                                                  float* __restrict__ osum,
                                                  float* __restrict__ osq) {
  constexpr int INFL_BYTES = MAXE * 16 * 4;     // 24,576
  constexpr int UNION_BYTES = 16 * AGP * 2;     // 30,976 > 24,576 + 1,536
  __shared__ __align__(16) char uSm[UNION_BYTES];
  __shared__ int qoffL[17];
  __shared__ float kpL[48];
  __shared__ int actC[16];
  __shared__ int qA[17];
  float* inflF = (float*)uSm;                   // compacted [nA][16], k=15 zeroed
  int* refsL = (int*)(uSm + INFL_BYTES);        // compacted [nA]
  __bf16* aggL = (__bf16*)uSm;                  // [16][AGP] (overlays the above)

  const int tid = threadIdx.x;
  const int q0 = blockIdx.x << 4;
  if (tid < 17) qoffL[tid] = off[q0 + tid];
  if (tid >= 32 && tid < 32 + 45) kpL[tid - 32] = kpts[tid - 32];
  if (tid >= 80 && tid < 96) actC[tid - 80] = 0;
  __syncthreads();

  const int e0 = qoffL[0];
  int nE = qoffL[16] - e0;
  if (nE > MAXE) nE = MAXE;

  // ---- pass A: influences -> regs, count actives per query ----
  float w0[16], w1[16];
  int ref0 = 0, ref1 = 0, lo0 = 0, lo1 = 0, rk0 = -1, rk1 = -1;
  if (tid < nE) {
    if (kp_infl(pos, sref, qoffL, kpL, e0 + tid, q0, ref0, lo0, w0))
      rk0 = atomicAdd(&actC[lo0], 1);
  }
  if (tid + 256 < nE) {
    if (kp_infl(pos, sref, qoffL, kpL, e0 + tid + 256, q0, ref1, lo1, w1))
      rk1 = atomicAdd(&actC[lo1], 1);
  }
  __syncthreads();
  if (tid == 0) {
    int run = 0;
#pragma unroll
    for (int k = 0; k < 16; ++k) { qA[k] = run; run += actC[k]; }
    qA[16] = run;
    if (run == 0) refsL[0] = 0;    // keep stage-2 prologue gather in-bounds
  }
  __syncthreads();

  // ---- pass B: scatter compacted active edges ----
  if (rk0 >= 0) {
    const int p = qA[lo0] + rk0;
    refsL[p] = ref0;
    *(float4*)&inflF[p * 16 + 0]  = make_float4(w0[0], w0[1], w0[2], w0[3]);
    *(float4*)&inflF[p * 16 + 4]  = make_float4(w0[4], w0[5], w0[6], w0[7]);
    *(float4*)&inflF[p * 16 + 8]  = make_float4(w0[8], w0[9], w0[10], w0[11]);
    *(float4*)&inflF[p * 16 + 12] = make_float4(w0[12], w0[13], w0[14], w0[15]);
  }
  if (rk1 >= 0) {
    const int p = qA[lo1] + rk1;
    refsL[p] = ref1;
    *(float4*)&inflF[p * 16 + 0]  = make_float4(w1[0], w1[1], w1[2], w1[3]);
    *(float4*)&inflF[p * 16 + 4]  = make_float4(w1[4], w1[5], w1[6], w1[7]);
    *(float4*)&inflF[p * 16 + 8]  = make_float4(w1[8], w1[9], w1[10], w1[11]);
    *(float4*)&inflF[p * 16 + 12] = make_float4(w1[12], w1[13], w1[14], w1[15]);
  }
  __syncthreads();

  // ---- stage 2: register accumulation over compacted edges ----
  const int wv = tid >> 6, lane = tid & 63;
  const int ql = (wv << 2) + (lane >> 4);   // query owned by this lane
  const int t4 = (lane & 15) << 2;          // channel chunk
  const int le0 = qA[ql];
  const int le1 = qA[ql + 1];
  const int len = le1 - le0;

  float acc[NK][4];
#pragma unroll
  for (int k = 0; k < NK; ++k) { acc[k][0] = acc[k][1] = acc[k][2] = acc[k][3] = 0.f; }

  // 2-deep h prefetch; ref index read one more iteration ahead.
  const int j0 = (len > 0) ? le0 : 0;
  const int j1 = (len > 1) ? le0 + 1 : j0;
  const int j2 = (len > 2) ? le0 + 2 : j1;
  bf4 hA = *(const bf4*)&hb[(size_t)refsL[j0] * 64 + t4];
  bf4 hB = *(const bf4*)&hb[(size_t)refsL[j1] * 64 + t4];
  int refC = refsL[j2];
#pragma unroll 1
  for (int j = le0; j < le1; ++j) {
    const bf4 hv = hA;
    hA = hB;
    hB = *(const bf4*)&hb[(size_t)refC * 64 + t4];   // prefetch j+2
    const int jn = (j + 3 < le1) ? j + 3 : le1 - 1;
    refC = refsL[jn];                                 // ref for j+3
    const float f0 = bf2f(hv[0]), f1 = bf2f(hv[1]), f2 = bf2f(hv[2]), f3 = bf2f(hv[3]);
    const float4 wA = *(const float4*)&inflF[j * 16 + 0];
    const float4 wB = *(const float4*)&inflF[j * 16 + 4];
    const float4 wC = *(const float4*)&inflF[j * 16 + 8];
    const float4 wD = *(const float4*)&inflF[j * 16 + 12];
    const float wk[NK] = {wA.x, wA.y, wA.z, wA.w, wB.x, wB.y, wB.z, wB.w,
                          wC.x, wC.y, wC.z, wC.w, wD.x, wD.y, wD.z};
#pragma unroll
    for (int k = 0; k < NK; ++k) {
      acc[k][0] += wk[k] * f0;
      acc[k][1] += wk[k] * f1;
      acc[k][2] += wk[k] * f2;
      acc[k][3] += wk[k] * f3;
    }
  }

  // inflF/refsL fully consumed by every wave before aggL overwrites the union
  __syncthreads();

  // write agg (bf16) for phase B
#pragma unroll
  for (int k = 0; k < NK; ++k) {
    bf4 o;
    o[0] = (__bf16)acc[k][0]; o[1] = (__bf16)acc[k][1];
    o[2] = (__bf16)acc[k][2]; o[3] = (__bf16)acc[k][3];
    *(bf4*)&aggL[ql * AGP + k * 64 + t4] = o;
  }
  __syncthreads();

  // ---- phase B: MFMA y = agg @ Wk, wave wv -> cols [wv*16, wv*16+16) ----
  const int m = lane & 15, quad = lane >> 4;
  v4f yacc = {0.f, 0.f, 0.f, 0.f};
  const v8bf* Wf8 = (const v8bf*)Wf;
#pragma unroll
  for (int k = 0; k < NK; ++k)
#pragma unroll
    for (int kb = 0; kb < 2; ++kb) {
      const v8bf av = *(const v8bf*)&aggL[m * AGP + k * 64 + kb * 32 + (quad << 3)];
      const v8bf bv = Wf8[((k * 2 + kb) * 4 + wv) * 64 + lane];
      yacc = __builtin_amdgcn_mfma_f32_16x16x32_bf16(av, bv, yacc, 0, 0, 0);
    }

  float s = 0.f, q2 = 0.f;
#pragma unroll
  for (int r = 0; r < 4; ++r) {
    const float v = yacc[r];
    y[(size_t)(q0 + (quad << 2) + r) * 64 + (wv << 4) + m] = v;
    s += v; q2 += v * v;
  }
  s += __shfl_down(s, 32); s += __shfl_down(s, 16);
  q2 += __shfl_down(q2, 32); q2 += __shfl_down(q2, 16);
  if (quad == 0) {
    atomicAdd(&osum[(wv << 4) + m], s);
    atomicAdd(&osq[(wv << 4) + m], q2);
  }
}

// ---------------------------------------------------------------------------
extern "C" void kernel_launch(void* const* d_in, const int* in_sizes, int n_in,
                              void* d_out, int out_size, void* d_ws, size_t ws_size,
                              hipStream_t stream) {
  const float* pos = (const float*)d_in[0];
  const float* x   = (const float*)d_in[1];
  const int* er    = (const int*)d_in[2];
  const int* eq    = (const int*)d_in[3];
  const float* W1  = (const float*)d_in[4];
  const float* g1  = (const float*)d_in[5];
  const float* b1  = (const float*)d_in[6];
  const float* kp  = (const float*)d_in[7];
  const float* Wkp = (const float*)d_in[8];
  const float* gkp = (const float*)d_in[9];
  const float* bkp = (const float*)d_in[10];
  const float* W2  = (const float*)d_in[11];
  const float* g2  = (const float*)d_in[12];
  const float* b2  = (const float*)d_in[13];
  const float* Wsc = (const float*)d_in[14];
  const float* gsc = (const float*)d_in[15];
  const float* bsc = (const float*)d_in[16];
  float* out = (float*)d_out;
  float* ws = (float*)d_ws;

  // stats / affine scratch (first 4096 floats)
  float* sum1 = ws;          float* sq1  = ws + 64;
  float* sumsc = ws + 128;   float* sqsc = ws + 384;
  float* sumy = ws + 640;    float* sqy  = ws + 704;
  float* sum2 = ws + 768;    float* sq2  = ws + 1024;
  float* a1v = ws + 1280;    float* b1v  = ws + 1344;
  float* ascv = ws + 1408;   float* bscv = ws + 1664;
  float* ayv = ws + 1920;    float* byv  = ws + 1984;
  float* a2v = ws + 2048;    float* b2v  = ws + 2304;

  // layout (float offsets)
  __bf16* Wpb = (__bf16*)(ws + 4096);            // preshuffled weights
  __bf16* W1p = Wpb;
  __bf16* Wscp = Wpb + 8192;
  __bf16* W2p = Wpb + 40960;
  __bf16* Wfp = Wpb + 57344;
  __bf16* hb = (__bf16*)(ws + 69632);            // bf16 [N*64]
  float* ybuf = ws + 69632 + 3200000;            // fp32 [N*64]
  float* t1bf = ybuf + 6400000;                  // bf16 t1 [N*64] region
  __bf16* t1b = (__bf16*)t1bf;
  __bf16* tscb = (__bf16*)ybuf;                  // bf16 [N*256] overlays ybuf+t1b
  int* cnt = (int*)(t1bf + 6400000);             // sort region
  int* off = cnt + 100352;
  int* cur = off + 100352;
  int* part = cur + 100352;
  int* sref = part + 256;
  __bf16* t2b = (__bf16*)cnt;                    // bf16 [N*256] overlays sort region

  const float invn = 1.f / (float)NP;

  (void)hipMemsetAsync(ws, 0, 4096 * sizeof(float), stream);
  (void)hipMemsetAsync(cnt, 0, 100352 * sizeof(int), stream);

  // weight preshuffle
  allshuf_k<<<464, 256, 0, stream>>>(W1, Wsc, W2, Wkp, Wpb);

  // unary_1: t1b = bf16(x@W1) (stats fused) ; fold ; hb = bf16(leaky(BN))
  mgemm_k<128, 64, false, true><<<dim3(782, 1), 256, 0, stream>>>(
      x, W1p, t1b, NP, 64, nullptr, nullptr, sum1, sq1);
  finalize_k<<<1, 256, 0, stream>>>(sum1, sq1, g1, b1, a1v, b1v, 64, invn);
  normleaky_k<<<6250, 256, 0, stream>>>(t1b, hb, a1v, b1v);

  // edge sort by query
  hist_k<<<2048, 256, 0, stream>>>(eq, cnt);
  scanA_k<<<SNB, 256, 0, stream>>>(cnt, part);
  scanB_k<<<1, 64, 0, stream>>>(part, off);
  scanC_k<<<SNB, 256, 0, stream>>>(cnt, part, off, cur);
  scat_k<<<2048, 256, 0, stream>>>(er, eq, cur, sref);

  // KPConv (y stats fused)
  kpagg_k<<<6250, 256, 0, stream>>>(pos, sref, off, kp, Wfp, hb, ybuf, sumy, sqy);
  finalize_k<<<1, 256, 0, stream>>>(sumy, sqy, gkp, bkp, ayv, byv, 64, invn);

  // unary_2: t2b = bf16( leaky(BN(y)) @ W2 ), stats fused (overwrites sort bufs)
  mgemm_k<64, 128, true, true><<<dim3(782, 2), 256, 0, stream>>>(
      ybuf, W2p, t2b, NP, 256, ayv, byv, sum2, sq2);
  finalize_k<<<1, 256, 0, stream>>>(sum2, sq2, g2, b2, a2v, b2v, 256, invn);

  // shortcut: tscb = bf16( x@Wsc ), stats fused (overwrites ybuf/t1b)
  mgemm_k<128, 128, false, true><<<dim3(782, 2), 256, 0, stream>>>(
      x, Wscp, tscb, NP, 256, nullptr, nullptr, sumsc, sqsc);
  finalize_k<<<1, 256, 0, stream>>>(sumsc, sqsc, gsc, bsc, ascv, bscv, 256, invn);

  // out = leaky(BN(t2)) + BN(tsc)
  final_k<<<25000, 256, 0, stream>>>(out, t2b, tscb, a2v, b2v, ascv, bscv);
}

// Round 5
// 621.441 us; speedup vs baseline: 1.2243x; 1.1916x over previous
//
#include <hip/hip_runtime.h>
#include <math.h>

#define NP   100000
#define EDG  1600000
#define NK   15
#define SIGK 0.04f
#define SCH  2048
#define SNB  49            // ceil(NP/SCH)
#define MAXE 384           // max edges per 16-query block (mean 256, sigma 16)
#define AGP  968           // agg pitch in bf16 (960 + 8 pad)

typedef __bf16 v8bf __attribute__((ext_vector_type(8)));
typedef __bf16 bf4  __attribute__((ext_vector_type(4)));
typedef float  v4f  __attribute__((ext_vector_type(4)));

__device__ __forceinline__ float lk(float v) { return v >= 0.f ? v : 0.1f * v; }
__device__ __forceinline__ float bf2f(__bf16 b) { return (float)b; }

// ---------------------------------------------------------------------------
// MFMA GEMM: Out[n x Ntot] = X[n x KIN] @ W, W preshuffled bf16 B-frags.
// Block 256 thr = 4 waves; tile 128 rows x NB cols. Column stats fused.
// Stats go to REPLICATED accumulators (32 replicas, blockIdx.x&31) to avoid
// same-cache-line atomic serialization at L2 (the r0-r3 ~170us floor).
// ---------------------------------------------------------------------------
template <int KIN, int NB, bool TRANS, bool OUTBF>
__global__ __launch_bounds__(256) void mgemm_k(const float* __restrict__ X,
                                               const __bf16* __restrict__ Wp,
                                               void* __restrict__ Out, int n, int Ntot,
                                               const float* __restrict__ ta,
                                               const float* __restrict__ tb,
                                               float* __restrict__ osum,
                                               float* __restrict__ osq) {
  constexpr int PITCH = KIN + 8;
  constexpr int NT = NB / 16;
  __shared__ __bf16 al[128 * PITCH];
  __shared__ float red[2][NB][4];
  const int tid = threadIdx.x;
  const int r0 = blockIdx.x << 7;
  const int nb0 = blockIdx.y * NB;

  constexpr int QKS = (KIN == 128) ? 5 : 4;  // log2(KIN/4)
  for (int idx = tid; idx < (128 << QKS); idx += 256) {
    const int r = idx >> QKS, q = (idx & ((1 << QKS) - 1)) << 2;
    const int row = r0 + r;
    float4 v = make_float4(0.f, 0.f, 0.f, 0.f);
    if (row < n) {
      v = *(const float4*)&X[(size_t)row * KIN + q];
      if (TRANS) {
        v.x = lk(ta[q + 0] * v.x + tb[q + 0]);
        v.y = lk(ta[q + 1] * v.y + tb[q + 1]);
        v.z = lk(ta[q + 2] * v.z + tb[q + 2]);
        v.w = lk(ta[q + 3] * v.w + tb[q + 3]);
      }
    }
    bf4 o;
    o[0] = (__bf16)v.x; o[1] = (__bf16)v.y; o[2] = (__bf16)v.z; o[3] = (__bf16)v.w;
    *(bf4*)&al[r * PITCH + q] = o;
  }
  __syncthreads();

  const int wv = tid >> 6, lane = tid & 63;
  const int mr = lane & 15, quad = lane >> 4;
  const int ntg0 = nb0 >> 4;
  const int NTG = Ntot >> 4;
  v4f acc[2][NT];
#pragma unroll
  for (int a = 0; a < 2; ++a)
#pragma unroll
    for (int b = 0; b < NT; ++b) acc[a][b] = (v4f){0.f, 0.f, 0.f, 0.f};

#pragma unroll
  for (int ks = 0; ks < KIN / 32; ++ks) {
    v8bf bf[NT];
#pragma unroll
    for (int nt = 0; nt < NT; ++nt)
      bf[nt] = ((const v8bf*)Wp)[((size_t)ks * NTG + ntg0 + nt) * 64 + lane];
#pragma unroll
    for (int mt = 0; mt < 2; ++mt) {
      const int row = (wv << 5) + (mt << 4) + mr;
      const v8bf av = *(const v8bf*)&al[row * PITCH + (ks << 5) + (quad << 3)];
#pragma unroll
      for (int nt = 0; nt < NT; ++nt)
        acc[mt][nt] = __builtin_amdgcn_mfma_f32_16x16x32_bf16(av, bf[nt], acc[mt][nt], 0, 0, 0);
    }
  }

  float csum[NT], csq[NT];
#pragma unroll
  for (int nt = 0; nt < NT; ++nt) { csum[nt] = 0.f; csq[nt] = 0.f; }
#pragma unroll
  for (int mt = 0; mt < 2; ++mt)
#pragma unroll
    for (int nt = 0; nt < NT; ++nt)
#pragma unroll
      for (int r = 0; r < 4; ++r) {
        const float v = acc[mt][nt][r];
        const int row = r0 + (wv << 5) + (mt << 4) + (quad << 2) + r;
        if (row < n) {
          const size_t o = (size_t)row * Ntot + nb0 + (nt << 4) + mr;
          if (OUTBF) ((__bf16*)Out)[o] = (__bf16)v;
          else       ((float*)Out)[o] = v;
        }
        csum[nt] += v;
        csq[nt] += v * v;
      }
#pragma unroll
  for (int nt = 0; nt < NT; ++nt) {
    float s = csum[nt], q = csq[nt];
    s += __shfl_down(s, 32); s += __shfl_down(s, 16);
    q += __shfl_down(q, 32); q += __shfl_down(q, 16);
    if (quad == 0) { red[0][(nt << 4) + mr][wv] = s; red[1][(nt << 4) + mr][wv] = q; }
  }
  __syncthreads();
  if (tid < NB) {
    const float s = red[0][tid][0] + red[0][tid][1] + red[0][tid][2] + red[0][tid][3];
    const float q = red[1][tid][0] + red[1][tid][1] + red[1][tid][2] + red[1][tid][3];
    const int rep = (blockIdx.x & 31) * Ntot;   // replica row: kills hot-line atomics
    atomicAdd(&osum[rep + nb0 + tid], s);
    atomicAdd(&osq[rep + nb0 + tid], q);
  }
}

// ---------------------------------------------------------------------------
// Replica-reducing finalize: sum/sq are [R][C]; thread c reduces R replicas.
// ---------------------------------------------------------------------------
__global__ void finalize_k(const float* __restrict__ sum, const float* __restrict__ sq,
                           const float* __restrict__ g, const float* __restrict__ b,
                           float* __restrict__ oa, float* __restrict__ ob, int C, int R,
                           float invn) {
  const int c = threadIdx.x;
  if (c < C) {
    float s = 0.f, q = 0.f;
    for (int r = 0; r < R; ++r) { s += sum[r * C + c]; q += sq[r * C + c]; }
    const float m = s * invn;
    const float var = q * invn - m * m;
    const float a = g[c] / sqrtf(var + 1e-5f);
    oa[c] = a;
    ob[c] = b[c] - m * a;
  }
}

// t1 bf16 -> hb bf16 with affine+leaky
__global__ __launch_bounds__(256) void normleaky_k(const __bf16* __restrict__ t,
                                                   __bf16* __restrict__ hb,
                                                   const float* __restrict__ a,
                                                   const float* __restrict__ b) {
  const int idx = (blockIdx.x << 8) + threadIdx.x;
  const int c = (idx << 2) & 63;
  const bf4 v = *(const bf4*)&t[(size_t)idx << 2];
  bf4 o;
  o[0] = (__bf16)lk(a[c + 0] * bf2f(v[0]) + b[c + 0]);
  o[1] = (__bf16)lk(a[c + 1] * bf2f(v[1]) + b[c + 1]);
  o[2] = (__bf16)lk(a[c + 2] * bf2f(v[2]) + b[c + 2]);
  o[3] = (__bf16)lk(a[c + 3] * bf2f(v[3]) + b[c + 3]);
  *(bf4*)&hb[(size_t)idx << 2] = o;
}

// out = leaky(a2*t2+b2) + asc*tsc+bsc   (t2, tsc bf16)
__global__ __launch_bounds__(256) void final_k(float* __restrict__ o,
                                               const __bf16* __restrict__ t2,
                                               const __bf16* __restrict__ tsc,
                                               const float* __restrict__ a2,
                                               const float* __restrict__ b2,
                                               const float* __restrict__ asc,
                                               const float* __restrict__ bsc) {
  const int idx = (blockIdx.x << 8) + threadIdx.x;
  const int c = (idx << 2) & 255;
  const bf4 tv = *(const bf4*)&t2[(size_t)idx << 2];
  const bf4 sv = *(const bf4*)&tsc[(size_t)idx << 2];
  float4 r;
  r.x = lk(a2[c + 0] * bf2f(tv[0]) + b2[c + 0]) + asc[c + 0] * bf2f(sv[0]) + bsc[c + 0];
  r.y = lk(a2[c + 1] * bf2f(tv[1]) + b2[c + 1]) + asc[c + 1] * bf2f(sv[1]) + bsc[c + 1];
  r.z = lk(a2[c + 2] * bf2f(tv[2]) + b2[c + 2]) + asc[c + 2] * bf2f(sv[2]) + bsc[c + 2];
  r.w = lk(a2[c + 3] * bf2f(tv[3]) + b2[c + 3]) + asc[c + 3] * bf2f(sv[3]) + bsc[c + 3];
  ((float4*)o)[idx] = r;
}

// ---------------------------------------------------------------------------
// Counting sort of edges by e_query
// ---------------------------------------------------------------------------
__global__ __launch_bounds__(256) void hist_k(const int* __restrict__ eq, int* __restrict__ cnt) {
  const int stride = gridDim.x << 8;
  for (int e = (blockIdx.x << 8) + threadIdx.x; e < EDG; e += stride)
    atomicAdd(&cnt[eq[e]], 1);
}

__global__ __launch_bounds__(256) void scanA_k(const int* __restrict__ cnt, int* __restrict__ part) {
  __shared__ int s[256];
  const int tid = threadIdx.x;
  const int base = blockIdx.x * SCH;
  int acc = 0;
  for (int i = tid; i < SCH; i += 256) {
    const int idx = base + i;
    if (idx < NP) acc += cnt[idx];
  }
  s[tid] = acc;
  __syncthreads();
  for (int d = 128; d > 0; d >>= 1) {
    if (tid < d) s[tid] += s[tid + d];
    __syncthreads();
  }
  if (tid == 0) part[blockIdx.x] = s[0];
}

__global__ void scanB_k(int* __restrict__ part, int* __restrict__ off) {
  if (threadIdx.x == 0) {
    int run = 0;
    for (int i = 0; i < SNB; ++i) { const int v = part[i]; part[i] = run; run += v; }
    off[NP] = EDG;
  }
}

__global__ __launch_bounds__(256) void scanC_k(const int* __restrict__ cnt,
                                               const int* __restrict__ part,
                                               int* __restrict__ off, int* __restrict__ cur) {
  __shared__ int s[256];
  const int tid = threadIdx.x;
  const int base = blockIdx.x * SCH + tid * 8;
  int loc[8];
  int mysum = 0;
#pragma unroll
  for (int j = 0; j < 8; ++j) {
    const int idx = base + j;
    const int v = (idx < NP) ? cnt[idx] : 0;
    loc[j] = mysum;
    mysum += v;
  }
  s[tid] = mysum;
  __syncthreads();
  for (int d = 1; d < 256; d <<= 1) {
    int v = (tid >= d) ? s[tid - d] : 0;
    __syncthreads();
    s[tid] += v;
    __syncthreads();
  }
  const int tb = part[blockIdx.x] + s[tid] - mysum;
#pragma unroll
  for (int j = 0; j < 8; ++j) {
    const int idx = base + j;
    if (idx < NP) { off[idx] = tb + loc[j]; cur[idx] = tb + loc[j]; }
  }
}

__global__ __launch_bounds__(256) void scat_k(const int* __restrict__ er,
                                              const int* __restrict__ eq,
                                              int* __restrict__ cur, int* __restrict__ sref) {
  const int stride = gridDim.x << 8;
  for (int e = (blockIdx.x << 8) + threadIdx.x; e < EDG; e += stride) {
    const int p = atomicAdd(&cur[eq[e]], 1);
    sref[p] = er[e];
  }
}

// ---------------------------------------------------------------------------
// One-shot preshuffle of all weights into bf16 MFMA B-frag layouts.
// ---------------------------------------------------------------------------
__device__ __forceinline__ void wshuf1(const float* W, __bf16* Wp, int idx, int Ntot) {
  const int j = idx & 7;
  const int lane = (idx >> 3) & 63;
  const int rest = idx >> 9;
  const int NTG = Ntot >> 4;
  const int ntg = rest % NTG;
  const int ks = rest / NTG;
  Wp[idx] = (__bf16)W[(size_t)(ks * 32 + ((lane >> 4) << 3) + j) * Ntot + ntg * 16 + (lane & 15)];
}

__global__ __launch_bounds__(256) void allshuf_k(const float* __restrict__ W1,
                                                 const float* __restrict__ Wsc,
                                                 const float* __restrict__ W2,
                                                 const float* __restrict__ Wkp,
                                                 __bf16* __restrict__ base) {
  const int i = (blockIdx.x << 8) + threadIdx.x;
  if (i < 8192) {
    wshuf1(W1, base, i, 64);
  } else if (i < 40960) {
    wshuf1(Wsc, base + 8192, i - 8192, 256);
  } else if (i < 57344) {
    wshuf1(W2, base + 40960, i - 40960, 256);
  } else if (i < 118784) {
    const int idx = i - 57344;
    const int j = idx & 7;
    const int lane = (idx >> 3) & 63;
    const int nt = (idx >> 9) & 3;
    const int kb = (idx >> 11) & 1;
    const int k = idx >> 12;
    const int kd = kb * 32 + ((lane >> 4) << 3) + j;
    const int n = nt * 16 + (lane & 15);
    (base + 57344)[idx] = (__bf16)Wkp[(k * 64 + kd) * 64 + n];
  }
}

// ---------------------------------------------------------------------------
// Per-edge influence helper: fills w[0..15] (w[15]=0 pad), returns true if any
// kernel point is active for this edge.
// ---------------------------------------------------------------------------
__device__ __forceinline__ bool kp_infl(const float* __restrict__ pos,
                                        const int* __restrict__ sref,
                                        const int* qoffL, const float* kpL,
                                        int e, int q0, int& ref, int& lo, float* w) {
  ref = sref[e];
  int l = 0, h = 16;
  while (h - l > 1) { const int mid = (l + h) >> 1; if (qoffL[mid] <= e) l = mid; else h = mid; }
  lo = l;
  const float4 pr = *(const float4*)&pos[ref * 4];
  const float4 pq = *(const float4*)&pos[(q0 + l) * 4];
  const float rx = pr.y - pq.y, ry = pr.z - pq.z, rz = pr.w - pq.w;
  bool act = false;
#pragma unroll
  for (int k = 0; k < NK; ++k) {
    const float dx = rx - kpL[k * 3 + 0];
    const float dy = ry - kpL[k * 3 + 1];
    const float dz = rz - kpL[k * 3 + 2];
    const float v = 1.f - sqrtf(dx * dx + dy * dy + dz * dz) * (1.f / SIGK);
    const float wv = v > 0.f ? v : 0.f;
    w[k] = wv;
    act = act || (wv > 0.f);
  }
  w[15] = 0.f;
  return act;
}

// ---------------------------------------------------------------------------
// KPConv gather: block = 16 queries (256 thr). Active-edge compaction (pass A
// influences -> regs + rank atomics; pass B scatter; stage 2 over compacted
// edges with 2-deep hb prefetch). LDS union 31.3 KB. Phase B: MFMA y = agg@Wk.
// Column stats -> 64-replica accumulators (blockIdx.x&63): the r0-r3 ~170us
// floor was 6250 blocks x 16 atomics per cache line serializing at L2.
// ---------------------------------------------------------------------------
__global__ __launch_bounds__(256, 4) void kpagg_k(const float* __restrict__ pos,
                                                  const int* __restrict__ sref,
                                                  const int* __restrict__ off,
                                                  const float* __restrict__ kpts,
                                                  const __bf16* __restrict__ Wf,
                                                  const __bf16* __restrict__ hb,
                                                  float* __restrict__ y,
                                                  float* __restrict__ osum,
                                                  float* __restrict__ osq) {
  constexpr int INFL_BYTES = MAXE * 16 * 4;     // 24,576
  constexpr int UNION_BYTES = 16 * AGP * 2;     // 30,976 > 24,576 + 1,536
  __shared__ __align__(16) char uSm[UNION_BYTES];
  __shared__ int qoffL[17];
  __shared__ float kpL[48];
  __shared__ int actC[16];
  __shared__ int qA[17];
  float* inflF = (float*)uSm;                   // compacted [nA][16], k=15 zeroed
  int* refsL = (int*)(uSm + INFL_BYTES);        // compacted [nA]
  __bf16* aggL = (__bf16*)uSm;                  // [16][AGP] (overlays the above)

  const int tid = threadIdx.x;
  const int q0 = blockIdx.x << 4;
  if (tid < 17) qoffL[tid] = off[q0 + tid];
  if (tid >= 32 && tid < 32 + 45) kpL[tid - 32] = kpts[tid - 32];
  if (tid >= 80 && tid < 96) actC[tid - 80] = 0;
  __syncthreads();

  const int e0 = qoffL[0];
  int nE = qoffL[16] - e0;
  if (nE > MAXE) nE = MAXE;

  // ---- pass A: influences -> regs, count actives per query ----
  float w0[16], w1[16];
  int ref0 = 0, ref1 = 0, lo0 = 0, lo1 = 0, rk0 = -1, rk1 = -1;
  if (tid < nE) {
    if (kp_infl(pos, sref, qoffL, kpL, e0 + tid, q0, ref0, lo0, w0))
      rk0 = atomicAdd(&actC[lo0], 1);
  }
  if (tid + 256 < nE) {
    if (kp_infl(pos, sref, qoffL, kpL, e0 + tid + 256, q0, ref1, lo1, w1))
      rk1 = atomicAdd(&actC[lo1], 1);
  }
  __syncthreads();
  if (tid == 0) {
    int run = 0;
#pragma unroll
    for (int k = 0; k < 16; ++k) { qA[k] = run; run += actC[k]; }
    qA[16] = run;
    if (run == 0) refsL[0] = 0;    // keep stage-2 prologue gather in-bounds
  }
  __syncthreads();

  // ---- pass B: scatter compacted active edges ----
  if (rk0 >= 0) {
    const int p = qA[lo0] + rk0;
    refsL[p] = ref0;
    *(float4*)&inflF[p * 16 + 0]  = make_float4(w0[0], w0[1], w0[2], w0[3]);
    *(float4*)&inflF[p * 16 + 4]  = make_float4(w0[4], w0[5], w0[6], w0[7]);
    *(float4*)&inflF[p * 16 + 8]  = make_float4(w0[8], w0[9], w0[10], w0[11]);
    *(float4*)&inflF[p * 16 + 12] = make_float4(w0[12], w0[13], w0[14], w0[15]);
  }
  if (rk1 >= 0) {
    const int p = qA[lo1] + rk1;
    refsL[p] = ref1;
    *(float4*)&inflF[p * 16 + 0]  = make_float4(w1[0], w1[1], w1[2], w1[3]);
    *(float4*)&inflF[p * 16 + 4]  = make_float4(w1[4], w1[5], w1[6], w1[7]);
    *(float4*)&inflF[p * 16 + 8]  = make_float4(w1[8], w1[9], w1[10], w1[11]);
    *(float4*)&inflF[p * 16 + 12] = make_float4(w1[12], w1[13], w1[14], w1[15]);
  }
  __syncthreads();

  // ---- stage 2: register accumulation over compacted edges ----
  const int wv = tid >> 6, lane = tid & 63;
  const int ql = (wv << 2) + (lane >> 4);   // query owned by this lane
  const int t4 = (lane & 15) << 2;          // channel chunk
  const int le0 = qA[ql];
  const int le1 = qA[ql + 1];
  const int len = le1 - le0;

  float acc[NK][4];
#pragma unroll
  for (int k = 0; k < NK; ++k) { acc[k][0] = acc[k][1] = acc[k][2] = acc[k][3] = 0.f; }

  // 2-deep h prefetch; ref index read one more iteration ahead.
  const int j0 = (len > 0) ? le0 : 0;
  const int j1 = (len > 1) ? le0 + 1 : j0;
  const int j2 = (len > 2) ? le0 + 2 : j1;
  bf4 hA = *(const bf4*)&hb[(size_t)refsL[j0] * 64 + t4];
  bf4 hB = *(const bf4*)&hb[(size_t)refsL[j1] * 64 + t4];
  int refC = refsL[j2];
#pragma unroll 1
  for (int j = le0; j < le1; ++j) {
    const bf4 hv = hA;
    hA = hB;
    hB = *(const bf4*)&hb[(size_t)refC * 64 + t4];   // prefetch j+2
    const int jn = (j + 3 < le1) ? j + 3 : le1 - 1;
    refC = refsL[jn];                                 // ref for j+3
    const float f0 = bf2f(hv[0]), f1 = bf2f(hv[1]), f2 = bf2f(hv[2]), f3 = bf2f(hv[3]);
    const float4 wA = *(const float4*)&inflF[j * 16 + 0];
    const float4 wB = *(const float4*)&inflF[j * 16 + 4];
    const float4 wC = *(const float4*)&inflF[j * 16 + 8];
    const float4 wD = *(const float4*)&inflF[j * 16 + 12];
    const float wk[NK] = {wA.x, wA.y, wA.z, wA.w, wB.x, wB.y, wB.z, wB.w,
                          wC.x, wC.y, wC.z, wC.w, wD.x, wD.y, wD.z};
#pragma unroll
    for (int k = 0; k < NK; ++k) {
      acc[k][0] += wk[k] * f0;
      acc[k][1] += wk[k] * f1;
      acc[k][2] += wk[k] * f2;
      acc[k][3] += wk[k] * f3;
    }
  }

  // inflF/refsL fully consumed by every wave before aggL overwrites the union
  __syncthreads();

  // write agg (bf16) for phase B
#pragma unroll
  for (int k = 0; k < NK; ++k) {
    bf4 o;
    o[0] = (__bf16)acc[k][0]; o[1] = (__bf16)acc[k][1];
    o[2] = (__bf16)acc[k][2]; o[3] = (__bf16)acc[k][3];
    *(bf4*)&aggL[ql * AGP + k * 64 + t4] = o;
  }
  __syncthreads();

  // ---- phase B: MFMA y = agg @ Wk, wave wv -> cols [wv*16, wv*16+16) ----
  const int m = lane & 15, quad = lane >> 4;
  v4f yacc = {0.f, 0.f, 0.f, 0.f};
  const v8bf* Wf8 = (const v8bf*)Wf;
#pragma unroll
  for (int k = 0; k < NK; ++k)
#pragma unroll
    for (int kb = 0; kb < 2; ++kb) {
      const v8bf av = *(const v8bf*)&aggL[m * AGP + k * 64 + kb * 32 + (quad << 3)];
      const v8bf bv = Wf8[((k * 2 + kb) * 4 + wv) * 64 + lane];
      yacc = __builtin_amdgcn_mfma_f32_16x16x32_bf16(av, bv, yacc, 0, 0, 0);
    }

  float s = 0.f, q2 = 0.f;
#pragma unroll
  for (int r = 0; r < 4; ++r) {
    const float v = yacc[r];
    y[(size_t)(q0 + (quad << 2) + r) * 64 + (wv << 4) + m] = v;
    s += v; q2 += v * v;
  }
  s += __shfl_down(s, 32); s += __shfl_down(s, 16);
  q2 += __shfl_down(q2, 32); q2 += __shfl_down(q2, 16);
  if (quad == 0) {
    const int rep = (blockIdx.x & 63) << 6;   // replica row: kills hot-line atomics
    atomicAdd(&osum[rep + (wv << 4) + m], s);
    atomicAdd(&osq[rep + (wv << 4) + m], q2);
  }
}

// ---------------------------------------------------------------------------
extern "C" void kernel_launch(void* const* d_in, const int* in_sizes, int n_in,
                              void* d_out, int out_size, void* d_ws, size_t ws_size,
                              hipStream_t stream) {
  const float* pos = (const float*)d_in[0];
  const float* x   = (const float*)d_in[1];
  const int* er    = (const int*)d_in[2];
  const int* eq    = (const int*)d_in[3];
  const float* W1  = (const float*)d_in[4];
  const float* g1  = (const float*)d_in[5];
  const float* b1  = (const float*)d_in[6];
  const float* kp  = (const float*)d_in[7];
  const float* Wkp = (const float*)d_in[8];
  const float* gkp = (const float*)d_in[9];
  const float* bkp = (const float*)d_in[10];
  const float* W2  = (const float*)d_in[11];
  const float* g2  = (const float*)d_in[12];
  const float* b2  = (const float*)d_in[13];
  const float* Wsc = (const float*)d_in[14];
  const float* gsc = (const float*)d_in[15];
  const float* bsc = (const float*)d_in[16];
  float* out = (float*)d_out;
  float* ws = (float*)d_ws;

  // stats / affine scratch (replicated accumulators), first 49152 floats
  float* sum1 = ws;              // [32][64]
  float* sq1  = ws + 2048;       // [32][64]
  float* sumsc = ws + 4096;      // [32][256]
  float* sqsc  = ws + 12288;     // [32][256]
  float* sumy = ws + 20480;      // [64][64]
  float* sqy  = ws + 24576;      // [64][64]
  float* sum2 = ws + 28672;      // [32][256]
  float* sq2  = ws + 36864;      // [32][256]
  float* a1v = ws + 45056;   float* b1v  = ws + 45120;
  float* ascv = ws + 45184;  float* bscv = ws + 45440;
  float* ayv = ws + 45696;   float* byv  = ws + 45760;
  float* a2v = ws + 45824;   float* b2v  = ws + 46080;

  // layout (float offsets)
  __bf16* Wpb = (__bf16*)(ws + 49152);           // preshuffled weights
  __bf16* W1p = Wpb;
  __bf16* Wscp = Wpb + 8192;
  __bf16* W2p = Wpb + 40960;
  __bf16* Wfp = Wpb + 57344;
  __bf16* hb = (__bf16*)(ws + 114688);           // bf16 [N*64]
  float* ybuf = ws + 114688 + 3200000;           // fp32 [N*64]
  float* t1bf = ybuf + 6400000;                  // bf16 t1 [N*64] region
  __bf16* t1b = (__bf16*)t1bf;
  __bf16* tscb = (__bf16*)ybuf;                  // bf16 [N*256] overlays ybuf+t1b
  int* cnt = (int*)(t1bf + 6400000);             // sort region
  int* off = cnt + 100352;
  int* cur = off + 100352;
  int* part = cur + 100352;
  int* sref = part + 256;
  __bf16* t2b = (__bf16*)cnt;                    // bf16 [N*256] overlays sort region

  const float invn = 1.f / (float)NP;

  (void)hipMemsetAsync(ws, 0, 49152 * sizeof(float), stream);
  (void)hipMemsetAsync(cnt, 0, 100352 * sizeof(int), stream);

  // weight preshuffle
  allshuf_k<<<464, 256, 0, stream>>>(W1, Wsc, W2, Wkp, Wpb);

  // unary_1: t1b = bf16(x@W1) (stats fused) ; fold ; hb = bf16(leaky(BN))
  mgemm_k<128, 64, false, true><<<dim3(782, 1), 256, 0, stream>>>(
      x, W1p, t1b, NP, 64, nullptr, nullptr, sum1, sq1);
  finalize_k<<<1, 256, 0, stream>>>(sum1, sq1, g1, b1, a1v, b1v, 64, 32, invn);
  normleaky_k<<<6250, 256, 0, stream>>>(t1b, hb, a1v, b1v);

  // edge sort by query
  hist_k<<<2048, 256, 0, stream>>>(eq, cnt);
  scanA_k<<<SNB, 256, 0, stream>>>(cnt, part);
  scanB_k<<<1, 64, 0, stream>>>(part, off);
  scanC_k<<<SNB, 256, 0, stream>>>(cnt, part, off, cur);
  scat_k<<<2048, 256, 0, stream>>>(er, eq, cur, sref);

  // KPConv (y stats fused, 64 replicas)
  kpagg_k<<<6250, 256, 0, stream>>>(pos, sref, off, kp, Wfp, hb, ybuf, sumy, sqy);
  finalize_k<<<1, 256, 0, stream>>>(sumy, sqy, gkp, bkp, ayv, byv, 64, 64, invn);

  // unary_2: t2b = bf16( leaky(BN(y)) @ W2 ), stats fused (overwrites sort bufs)
  mgemm_k<64, 128, true, true><<<dim3(782, 2), 256, 0, stream>>>(
      ybuf, W2p, t2b, NP, 256, ayv, byv, sum2, sq2);
  finalize_k<<<1, 256, 0, stream>>>(sum2, sq2, g2, b2, a2v, b2v, 256, 32, invn);

  // shortcut: tscb = bf16( x@Wsc ), stats fused (overwrites ybuf/t1b)
  mgemm_k<128, 128, false, true><<<dim3(782, 2), 256, 0, stream>>>(
      x, Wscp, tscb, NP, 256, nullptr, nullptr, sumsc, sqsc);
  finalize_k<<<1, 256, 0, stream>>>(sumsc, sqsc, gsc, bsc, ascv, bscv, 256, 32, invn);

  // out = leaky(BN(t2)) + BN(tsc)
  final_k<<<25000, 256, 0, stream>>>(out, t2b, tscb, a2v, b2v, ascv, bscv);
}

// Round 6
// 518.963 us; speedup vs baseline: 1.4660x; 1.1975x over previous
//
#include <hip/hip_runtime.h>
#include <math.h>

#define NP   100000
#define EDG  1600000
#define NK   15
#define SIGK 0.04f
#define SCH  2048
#define SNB  49            // ceil(NP/SCH)
#define MAXE 384           // max ACTIVE edges per 16-query block (total mean 256, active mean ~120)
#define AGP  968           // agg pitch in bf16 (960 + 8 pad)

typedef __bf16 v8bf __attribute__((ext_vector_type(8)));
typedef __bf16 bf4  __attribute__((ext_vector_type(4)));
typedef float  v4f  __attribute__((ext_vector_type(4)));

__device__ __forceinline__ float lk(float v) { return v >= 0.f ? v : 0.1f * v; }
__device__ __forceinline__ float bf2f(__bf16 b) { return (float)b; }

// ---------------------------------------------------------------------------
// MFMA GEMM: Out[n x Ntot] = X[n x KIN] @ W, W preshuffled bf16 B-frags.
// Block 256 thr = 4 waves; tile 128 rows x NB cols. Column stats fused.
// Stats -> replicated accumulators (32 replicas) to avoid hot-line atomics.
// ---------------------------------------------------------------------------
template <int KIN, int NB, bool TRANS, bool OUTBF>
__global__ __launch_bounds__(256) void mgemm_k(const float* __restrict__ X,
                                               const __bf16* __restrict__ Wp,
                                               void* __restrict__ Out, int n, int Ntot,
                                               const float* __restrict__ ta,
                                               const float* __restrict__ tb,
                                               float* __restrict__ osum,
                                               float* __restrict__ osq) {
  constexpr int PITCH = KIN + 8;
  constexpr int NT = NB / 16;
  __shared__ __bf16 al[128 * PITCH];
  __shared__ float red[2][NB][4];
  const int tid = threadIdx.x;
  const int r0 = blockIdx.x << 7;
  const int nb0 = blockIdx.y * NB;

  constexpr int QKS = (KIN == 128) ? 5 : 4;  // log2(KIN/4)
  for (int idx = tid; idx < (128 << QKS); idx += 256) {
    const int r = idx >> QKS, q = (idx & ((1 << QKS) - 1)) << 2;
    const int row = r0 + r;
    float4 v = make_float4(0.f, 0.f, 0.f, 0.f);
    if (row < n) {
      v = *(const float4*)&X[(size_t)row * KIN + q];
      if (TRANS) {
        v.x = lk(ta[q + 0] * v.x + tb[q + 0]);
        v.y = lk(ta[q + 1] * v.y + tb[q + 1]);
        v.z = lk(ta[q + 2] * v.z + tb[q + 2]);
        v.w = lk(ta[q + 3] * v.w + tb[q + 3]);
      }
    }
    bf4 o;
    o[0] = (__bf16)v.x; o[1] = (__bf16)v.y; o[2] = (__bf16)v.z; o[3] = (__bf16)v.w;
    *(bf4*)&al[r * PITCH + q] = o;
  }
  __syncthreads();

  const int wv = tid >> 6, lane = tid & 63;
  const int mr = lane & 15, quad = lane >> 4;
  const int ntg0 = nb0 >> 4;
  const int NTG = Ntot >> 4;
  v4f acc[2][NT];
#pragma unroll
  for (int a = 0; a < 2; ++a)
#pragma unroll
    for (int b = 0; b < NT; ++b) acc[a][b] = (v4f){0.f, 0.f, 0.f, 0.f};

#pragma unroll
  for (int ks = 0; ks < KIN / 32; ++ks) {
    v8bf bf[NT];
#pragma unroll
    for (int nt = 0; nt < NT; ++nt)
      bf[nt] = ((const v8bf*)Wp)[((size_t)ks * NTG + ntg0 + nt) * 64 + lane];
#pragma unroll
    for (int mt = 0; mt < 2; ++mt) {
      const int row = (wv << 5) + (mt << 4) + mr;
      const v8bf av = *(const v8bf*)&al[row * PITCH + (ks << 5) + (quad << 3)];
#pragma unroll
      for (int nt = 0; nt < NT; ++nt)
        acc[mt][nt] = __builtin_amdgcn_mfma_f32_16x16x32_bf16(av, bf[nt], acc[mt][nt], 0, 0, 0);
    }
  }

  float csum[NT], csq[NT];
#pragma unroll
  for (int nt = 0; nt < NT; ++nt) { csum[nt] = 0.f; csq[nt] = 0.f; }
#pragma unroll
  for (int mt = 0; mt < 2; ++mt)
#pragma unroll
    for (int nt = 0; nt < NT; ++nt)
#pragma unroll
      for (int r = 0; r < 4; ++r) {
        const float v = acc[mt][nt][r];
        const int row = r0 + (wv << 5) + (mt << 4) + (quad << 2) + r;
        if (row < n) {
          const size_t o = (size_t)row * Ntot + nb0 + (nt << 4) + mr;
          if (OUTBF) ((__bf16*)Out)[o] = (__bf16)v;
          else       ((float*)Out)[o] = v;
        }
        csum[nt] += v;
        csq[nt] += v * v;
      }
#pragma unroll
  for (int nt = 0; nt < NT; ++nt) {
    float s = csum[nt], q = csq[nt];
    s += __shfl_down(s, 32); s += __shfl_down(s, 16);
    q += __shfl_down(q, 32); q += __shfl_down(q, 16);
    if (quad == 0) { red[0][(nt << 4) + mr][wv] = s; red[1][(nt << 4) + mr][wv] = q; }
  }
  __syncthreads();
  if (tid < NB) {
    const float s = red[0][tid][0] + red[0][tid][1] + red[0][tid][2] + red[0][tid][3];
    const float q = red[1][tid][0] + red[1][tid][1] + red[1][tid][2] + red[1][tid][3];
    const int rep = (blockIdx.x & 31) * Ntot;   // replica row: kills hot-line atomics
    atomicAdd(&osum[rep + nb0 + tid], s);
    atomicAdd(&osq[rep + nb0 + tid], q);
  }
}

// ---------------------------------------------------------------------------
// Replica-reducing finalize: sum/sq are [R][C]; thread c reduces R replicas.
// ---------------------------------------------------------------------------
__global__ void finalize_k(const float* __restrict__ sum, const float* __restrict__ sq,
                           const float* __restrict__ g, const float* __restrict__ b,
                           float* __restrict__ oa, float* __restrict__ ob, int C, int R,
                           float invn) {
  const int c = threadIdx.x;
  if (c < C) {
    float s = 0.f, q = 0.f;
    for (int r = 0; r < R; ++r) { s += sum[r * C + c]; q += sq[r * C + c]; }
    const float m = s * invn;
    const float var = q * invn - m * m;
    const float a = g[c] / sqrtf(var + 1e-5f);
    oa[c] = a;
    ob[c] = b[c] - m * a;
  }
}

// t1 bf16 -> hb bf16 with affine+leaky
__global__ __launch_bounds__(256) void normleaky_k(const __bf16* __restrict__ t,
                                                   __bf16* __restrict__ hb,
                                                   const float* __restrict__ a,
                                                   const float* __restrict__ b) {
  const int idx = (blockIdx.x << 8) + threadIdx.x;
  const int c = (idx << 2) & 63;
  const bf4 v = *(const bf4*)&t[(size_t)idx << 2];
  bf4 o;
  o[0] = (__bf16)lk(a[c + 0] * bf2f(v[0]) + b[c + 0]);
  o[1] = (__bf16)lk(a[c + 1] * bf2f(v[1]) + b[c + 1]);
  o[2] = (__bf16)lk(a[c + 2] * bf2f(v[2]) + b[c + 2]);
  o[3] = (__bf16)lk(a[c + 3] * bf2f(v[3]) + b[c + 3]);
  *(bf4*)&hb[(size_t)idx << 2] = o;
}

// out = leaky(a2*t2+b2) + asc*tsc+bsc   (t2, tsc bf16)
__global__ __launch_bounds__(256) void final_k(float* __restrict__ o,
                                               const __bf16* __restrict__ t2,
                                               const __bf16* __restrict__ tsc,
                                               const float* __restrict__ a2,
                                               const float* __restrict__ b2,
                                               const float* __restrict__ asc,
                                               const float* __restrict__ bsc) {
  const int idx = (blockIdx.x << 8) + threadIdx.x;
  const int c = (idx << 2) & 255;
  const bf4 tv = *(const bf4*)&t2[(size_t)idx << 2];
  const bf4 sv = *(const bf4*)&tsc[(size_t)idx << 2];
  float4 r;
  r.x = lk(a2[c + 0] * bf2f(tv[0]) + b2[c + 0]) + asc[c + 0] * bf2f(sv[0]) + bsc[c + 0];
  r.y = lk(a2[c + 1] * bf2f(tv[1]) + b2[c + 1]) + asc[c + 1] * bf2f(sv[1]) + bsc[c + 1];
  r.z = lk(a2[c + 2] * bf2f(tv[2]) + b2[c + 2]) + asc[c + 2] * bf2f(sv[2]) + bsc[c + 2];
  r.w = lk(a2[c + 3] * bf2f(tv[3]) + b2[c + 3]) + asc[c + 3] * bf2f(sv[3]) + bsc[c + 3];
  ((float4*)o)[idx] = r;
}

// ---------------------------------------------------------------------------
// Edge activity test: true iff any kernel point has nonzero influence.
// kp in constant-ish global (45 floats, L2-resident).
// ---------------------------------------------------------------------------
__device__ __forceinline__ bool edge_active(const float* __restrict__ pos,
                                            const float* __restrict__ kp,
                                            int ref, int q) {
  const float4 pr = *(const float4*)&pos[ref * 4];
  const float4 pq = *(const float4*)&pos[q * 4];
  const float rx = pr.y - pq.y, ry = pr.z - pq.z, rz = pr.w - pq.w;
  bool act = false;
#pragma unroll
  for (int k = 0; k < NK; ++k) {
    const float dx = rx - kp[k * 3 + 0];
    const float dy = ry - kp[k * 3 + 1];
    const float dz = rz - kp[k * 3 + 2];
    act = act || (dx * dx + dy * dy + dz * dz < SIGK * SIGK);
  }
  return act;
}

// ---------------------------------------------------------------------------
// Counting sort of ACTIVE edges by e_query. Dead edges (~50%, zero influence)
// are filtered here: each scattered 4B write costs a 64B HBM line (r5 PMC:
// WRITE_SIZE 107MB for a 6.4MB payload), so halving the scatter halves scat_k.
// hist decides activity ONCE and stores a flag byte; scat reads the flag ->
// count/write agreement is exact.
// ---------------------------------------------------------------------------
__global__ __launch_bounds__(256) void hist_k(const int* __restrict__ er,
                                              const int* __restrict__ eq,
                                              const float* __restrict__ pos,
                                              const float* __restrict__ kp,
                                              int* __restrict__ cnt,
                                              unsigned char* __restrict__ flags) {
  const int stride = gridDim.x << 8;
  for (int e = (blockIdx.x << 8) + threadIdx.x; e < EDG; e += stride) {
    const int q = eq[e];
    const bool act = edge_active(pos, kp, er[e], q);
    flags[e] = act ? 1 : 0;
    if (act) atomicAdd(&cnt[q], 1);
  }
}

__global__ __launch_bounds__(256) void scanA_k(const int* __restrict__ cnt, int* __restrict__ part) {
  __shared__ int s[256];
  const int tid = threadIdx.x;
  const int base = blockIdx.x * SCH;
  int acc = 0;
  for (int i = tid; i < SCH; i += 256) {
    const int idx = base + i;
    if (idx < NP) acc += cnt[idx];
  }
  s[tid] = acc;
  __syncthreads();
  for (int d = 128; d > 0; d >>= 1) {
    if (tid < d) s[tid] += s[tid + d];
    __syncthreads();
  }
  if (tid == 0) part[blockIdx.x] = s[0];
}

__global__ void scanB_k(int* __restrict__ part, int* __restrict__ off) {
  if (threadIdx.x == 0) {
    int run = 0;
    for (int i = 0; i < SNB; ++i) { const int v = part[i]; part[i] = run; run += v; }
    off[NP] = run;              // total ACTIVE edges
  }
}

__global__ __launch_bounds__(256) void scanC_k(const int* __restrict__ cnt,
                                               const int* __restrict__ part,
                                               int* __restrict__ off, int* __restrict__ cur) {
  __shared__ int s[256];
  const int tid = threadIdx.x;
  const int base = blockIdx.x * SCH + tid * 8;
  int loc[8];
  int mysum = 0;
#pragma unroll
  for (int j = 0; j < 8; ++j) {
    const int idx = base + j;
    const int v = (idx < NP) ? cnt[idx] : 0;
    loc[j] = mysum;
    mysum += v;
  }
  s[tid] = mysum;
  __syncthreads();
  for (int d = 1; d < 256; d <<= 1) {
    int v = (tid >= d) ? s[tid - d] : 0;
    __syncthreads();
    s[tid] += v;
    __syncthreads();
  }
  const int tb = part[blockIdx.x] + s[tid] - mysum;
#pragma unroll
  for (int j = 0; j < 8; ++j) {
    const int idx = base + j;
    if (idx < NP) { off[idx] = tb + loc[j]; cur[idx] = tb + loc[j]; }
  }
}

__global__ __launch_bounds__(256) void scat_k(const int* __restrict__ er,
                                              const int* __restrict__ eq,
                                              const unsigned char* __restrict__ flags,
                                              int* __restrict__ cur, int* __restrict__ sref) {
  const int stride = gridDim.x << 8;
  for (int e = (blockIdx.x << 8) + threadIdx.x; e < EDG; e += stride) {
    if (flags[e]) {
      const int p = atomicAdd(&cur[eq[e]], 1);
      if (p < EDG) sref[p] = er[e];
    }
  }
}

// ---------------------------------------------------------------------------
// One-shot preshuffle of all weights into bf16 MFMA B-frag layouts.
// ---------------------------------------------------------------------------
__device__ __forceinline__ void wshuf1(const float* W, __bf16* Wp, int idx, int Ntot) {
  const int j = idx & 7;
  const int lane = (idx >> 3) & 63;
  const int rest = idx >> 9;
  const int NTG = Ntot >> 4;
  const int ntg = rest % NTG;
  const int ks = rest / NTG;
  Wp[idx] = (__bf16)W[(size_t)(ks * 32 + ((lane >> 4) << 3) + j) * Ntot + ntg * 16 + (lane & 15)];
}

__global__ __launch_bounds__(256) void allshuf_k(const float* __restrict__ W1,
                                                 const float* __restrict__ Wsc,
                                                 const float* __restrict__ W2,
                                                 const float* __restrict__ Wkp,
                                                 __bf16* __restrict__ base) {
  const int i = (blockIdx.x << 8) + threadIdx.x;
  if (i < 8192) {
    wshuf1(W1, base, i, 64);
  } else if (i < 40960) {
    wshuf1(Wsc, base + 8192, i - 8192, 256);
  } else if (i < 57344) {
    wshuf1(W2, base + 40960, i - 40960, 256);
  } else if (i < 118784) {
    const int idx = i - 57344;
    const int j = idx & 7;
    const int lane = (idx >> 3) & 63;
    const int nt = (idx >> 9) & 3;
    const int kb = (idx >> 11) & 1;
    const int k = idx >> 12;
    const int kd = kb * 32 + ((lane >> 4) << 3) + j;
    const int n = nt * 16 + (lane & 15);
    (base + 57344)[idx] = (__bf16)Wkp[(k * 64 + kd) * 64 + n];
  }
}

// ---------------------------------------------------------------------------
// KPConv gather: block = 16 queries (256 thr). The edge list is pre-filtered
// to active edges (hist/scat), so no in-kernel compaction. Stage 1: influence
// fill (mean ~120 edges/block). Stage 2: lane owns (query, 4-ch chunk);
// register acc[15][4]; broadcast LDS influence reads + 2-deep prefetched bf16
// h gather. LDS union 31.3 KB -> 4 blocks/CU. Phase B: MFMA y = agg @ Wk.
// Column stats -> 64-replica accumulators (hot-line atomics were the r0-r3
// ~170us floor).
// ---------------------------------------------------------------------------
__global__ __launch_bounds__(256, 4) void kpagg_k(const float* __restrict__ pos,
                                                  const int* __restrict__ sref,
                                                  const int* __restrict__ off,
                                                  const float* __restrict__ kpts,
                                                  const __bf16* __restrict__ Wf,
                                                  const __bf16* __restrict__ hb,
                                                  float* __restrict__ y,
                                                  float* __restrict__ osum,
                                                  float* __restrict__ osq) {
  constexpr int INFL_BYTES = MAXE * 16 * 4;     // 24,576
  constexpr int UNION_BYTES = 16 * AGP * 2;     // 30,976 > 24,576 + 1,536
  __shared__ __align__(16) char uSm[UNION_BYTES];
  __shared__ int qoffL[17];
  __shared__ float kpL[48];
  float* inflF = (float*)uSm;                   // [MAXE][16], k=15 zeroed
  int* refsL = (int*)(uSm + INFL_BYTES);        // [MAXE]
  __bf16* aggL = (__bf16*)uSm;                  // [16][AGP] (overlays the above)

  const int tid = threadIdx.x;
  const int q0 = blockIdx.x << 4;
  if (tid < 17) qoffL[tid] = off[q0 + tid];
  if (tid >= 32 && tid < 32 + 45) kpL[tid - 32] = kpts[tid - 32];
  __syncthreads();

  const int e0 = qoffL[0];
  int nE = qoffL[16] - e0;
  if (nE > MAXE) nE = MAXE;
  if (nE == 0 && tid == 0) refsL[0] = 0;        // keep stage-2 prologue in-bounds

  // ---- stage 1: influence fill over pre-filtered edges ----
  for (int i = tid; i < nE; i += 256) {
    const int e = e0 + i;
    const int ref = sref[e];
    refsL[i] = ref;
    int lo = 0, hi = 16;
    while (hi - lo > 1) { const int mid = (lo + hi) >> 1; if (qoffL[mid] <= e) lo = mid; else hi = mid; }
    const int q = q0 + lo;
    const float4 pr = *(const float4*)&pos[ref * 4];
    const float4 pq = *(const float4*)&pos[q * 4];
    const float rx = pr.y - pq.y, ry = pr.z - pq.z, rz = pr.w - pq.w;
    float wk[16];
#pragma unroll
    for (int k = 0; k < NK; ++k) {
      const float dx = rx - kpL[k * 3 + 0];
      const float dy = ry - kpL[k * 3 + 1];
      const float dz = rz - kpL[k * 3 + 2];
      const float w = 1.f - sqrtf(dx * dx + dy * dy + dz * dz) * (1.f / SIGK);
      wk[k] = w > 0.f ? w : 0.f;
    }
    wk[15] = 0.f;
    *(float4*)&inflF[i * 16 + 0]  = make_float4(wk[0], wk[1], wk[2], wk[3]);
    *(float4*)&inflF[i * 16 + 4]  = make_float4(wk[4], wk[5], wk[6], wk[7]);
    *(float4*)&inflF[i * 16 + 8]  = make_float4(wk[8], wk[9], wk[10], wk[11]);
    *(float4*)&inflF[i * 16 + 12] = make_float4(wk[12], wk[13], wk[14], wk[15]);
  }
  __syncthreads();

  // ---- stage 2: register accumulation ----
  const int wv = tid >> 6, lane = tid & 63;
  const int ql = (wv << 2) + (lane >> 4);   // query owned by this lane
  const int t4 = (lane & 15) << 2;          // channel chunk
  const int le0 = qoffL[ql] - e0;
  int le1 = qoffL[ql + 1] - e0;
  if (le1 > nE) le1 = nE;
  const int len = le1 - le0;

  float acc[NK][4];
#pragma unroll
  for (int k = 0; k < NK; ++k) { acc[k][0] = acc[k][1] = acc[k][2] = acc[k][3] = 0.f; }

  // 2-deep h prefetch; ref index read one more iteration ahead.
  const int j0 = (len > 0) ? le0 : 0;
  const int j1 = (len > 1) ? le0 + 1 : j0;
  const int j2 = (len > 2) ? le0 + 2 : j1;
  bf4 hA = *(const bf4*)&hb[(size_t)refsL[j0] * 64 + t4];
  bf4 hB = *(const bf4*)&hb[(size_t)refsL[j1] * 64 + t4];
  int refC = refsL[j2];
#pragma unroll 1
  for (int j = le0; j < le1; ++j) {
    const bf4 hv = hA;
    hA = hB;
    hB = *(const bf4*)&hb[(size_t)refC * 64 + t4];   // prefetch j+2
    const int jn = (j + 3 < le1) ? j + 3 : le1 - 1;
    refC = refsL[jn];                                 // ref for j+3
    const float f0 = bf2f(hv[0]), f1 = bf2f(hv[1]), f2 = bf2f(hv[2]), f3 = bf2f(hv[3]);
    const float4 wA = *(const float4*)&inflF[j * 16 + 0];
    const float4 wB = *(const float4*)&inflF[j * 16 + 4];
    const float4 wC = *(const float4*)&inflF[j * 16 + 8];
    const float4 wD = *(const float4*)&inflF[j * 16 + 12];
    const float wk[NK] = {wA.x, wA.y, wA.z, wA.w, wB.x, wB.y, wB.z, wB.w,
                          wC.x, wC.y, wC.z, wC.w, wD.x, wD.y, wD.z};
#pragma unroll
    for (int k = 0; k < NK; ++k) {
      acc[k][0] += wk[k] * f0;
      acc[k][1] += wk[k] * f1;
      acc[k][2] += wk[k] * f2;
      acc[k][3] += wk[k] * f3;
    }
  }

  // inflF/refsL fully consumed by every wave before aggL overwrites the union
  __syncthreads();

  // write agg (bf16) for phase B
#pragma unroll
  for (int k = 0; k < NK; ++k) {
    bf4 o;
    o[0] = (__bf16)acc[k][0]; o[1] = (__bf16)acc[k][1];
    o[2] = (__bf16)acc[k][2]; o[3] = (__bf16)acc[k][3];
    *(bf4*)&aggL[ql * AGP + k * 64 + t4] = o;
  }
  __syncthreads();

  // ---- phase B: MFMA y = agg @ Wk, wave wv -> cols [wv*16, wv*16+16) ----
  const int m = lane & 15, quad = lane >> 4;
  v4f yacc = {0.f, 0.f, 0.f, 0.f};
  const v8bf* Wf8 = (const v8bf*)Wf;
#pragma unroll
  for (int k = 0; k < NK; ++k)
#pragma unroll
    for (int kb = 0; kb < 2; ++kb) {
      const v8bf av = *(const v8bf*)&aggL[m * AGP + k * 64 + kb * 32 + (quad << 3)];
      const v8bf bv = Wf8[((k * 2 + kb) * 4 + wv) * 64 + lane];
      yacc = __builtin_amdgcn_mfma_f32_16x16x32_bf16(av, bv, yacc, 0, 0, 0);
    }

  float s = 0.f, q2 = 0.f;
#pragma unroll
  for (int r = 0; r < 4; ++r) {
    const float v = yacc[r];
    y[(size_t)(q0 + (quad << 2) + r) * 64 + (wv << 4) + m] = v;
    s += v; q2 += v * v;
  }
  s += __shfl_down(s, 32); s += __shfl_down(s, 16);
  q2 += __shfl_down(q2, 32); q2 += __shfl_down(q2, 16);
  if (quad == 0) {
    const int rep = (blockIdx.x & 63) << 6;   // replica row: kills hot-line atomics
    atomicAdd(&osum[rep + (wv << 4) + m], s);
    atomicAdd(&osq[rep + (wv << 4) + m], q2);
  }
}

// ---------------------------------------------------------------------------
extern "C" void kernel_launch(void* const* d_in, const int* in_sizes, int n_in,
                              void* d_out, int out_size, void* d_ws, size_t ws_size,
                              hipStream_t stream) {
  const float* pos = (const float*)d_in[0];
  const float* x   = (const float*)d_in[1];
  const int* er    = (const int*)d_in[2];
  const int* eq    = (const int*)d_in[3];
  const float* W1  = (const float*)d_in[4];
  const float* g1  = (const float*)d_in[5];
  const float* b1  = (const float*)d_in[6];
  const float* kp  = (const float*)d_in[7];
  const float* Wkp = (const float*)d_in[8];
  const float* gkp = (const float*)d_in[9];
  const float* bkp = (const float*)d_in[10];
  const float* W2  = (const float*)d_in[11];
  const float* g2  = (const float*)d_in[12];
  const float* b2  = (const float*)d_in[13];
  const float* Wsc = (const float*)d_in[14];
  const float* gsc = (const float*)d_in[15];
  const float* bsc = (const float*)d_in[16];
  float* out = (float*)d_out;
  float* ws = (float*)d_ws;

  // stats / affine scratch (replicated accumulators), first 49152 floats
  float* sum1 = ws;              // [32][64]
  float* sq1  = ws + 2048;       // [32][64]
  float* sumsc = ws + 4096;      // [32][256]
  float* sqsc  = ws + 12288;     // [32][256]
  float* sumy = ws + 20480;      // [64][64]
  float* sqy  = ws + 24576;      // [64][64]
  float* sum2 = ws + 28672;      // [32][256]
  float* sq2  = ws + 36864;      // [32][256]
  float* a1v = ws + 45056;   float* b1v  = ws + 45120;
  float* ascv = ws + 45184;  float* bscv = ws + 45440;
  float* ayv = ws + 45696;   float* byv  = ws + 45760;
  float* a2v = ws + 45824;   float* b2v  = ws + 46080;

  // layout (float offsets)
  __bf16* Wpb = (__bf16*)(ws + 49152);           // preshuffled weights
  __bf16* W1p = Wpb;
  __bf16* Wscp = Wpb + 8192;
  __bf16* W2p = Wpb + 40960;
  __bf16* Wfp = Wpb + 57344;
  __bf16* hb = (__bf16*)(ws + 114688);           // bf16 [N*64]
  float* ybuf = ws + 114688 + 3200000;           // fp32 [N*64]
  float* t1bf = ybuf + 6400000;                  // bf16 t1 [N*64] region
  __bf16* t1b = (__bf16*)t1bf;
  __bf16* tscb = (__bf16*)ybuf;                  // bf16 [N*256] overlays ybuf+t1b
  int* cnt = (int*)(t1bf + 6400000);             // sort region
  int* off = cnt + 100352;
  int* cur = off + 100352;
  int* part = cur + 100352;
  int* sref = part + 256;
  unsigned char* flags = (unsigned char*)(sref + EDG);   // [EDG] activity flags
  __bf16* t2b = (__bf16*)cnt;                    // bf16 [N*256] overlays sort region

  const float invn = 1.f / (float)NP;

  (void)hipMemsetAsync(ws, 0, 49152 * sizeof(float), stream);
  (void)hipMemsetAsync(cnt, 0, 100352 * sizeof(int), stream);

  // weight preshuffle
  allshuf_k<<<464, 256, 0, stream>>>(W1, Wsc, W2, Wkp, Wpb);

  // unary_1: t1b = bf16(x@W1) (stats fused) ; fold ; hb = bf16(leaky(BN))
  mgemm_k<128, 64, false, true><<<dim3(782, 1), 256, 0, stream>>>(
      x, W1p, t1b, NP, 64, nullptr, nullptr, sum1, sq1);
  finalize_k<<<1, 256, 0, stream>>>(sum1, sq1, g1, b1, a1v, b1v, 64, 32, invn);
  normleaky_k<<<6250, 256, 0, stream>>>(t1b, hb, a1v, b1v);

  // edge sort by query, ACTIVE edges only (flags decided once in hist)
  hist_k<<<2048, 256, 0, stream>>>(er, eq, pos, kp, cnt, flags);
  scanA_k<<<SNB, 256, 0, stream>>>(cnt, part);
  scanB_k<<<1, 64, 0, stream>>>(part, off);
  scanC_k<<<SNB, 256, 0, stream>>>(cnt, part, off, cur);
  scat_k<<<2048, 256, 0, stream>>>(er, eq, flags, cur, sref);

  // KPConv (y stats fused, 64 replicas)
  kpagg_k<<<6250, 256, 0, stream>>>(pos, sref, off, kp, Wfp, hb, ybuf, sumy, sqy);
  finalize_k<<<1, 256, 0, stream>>>(sumy, sqy, gkp, bkp, ayv, byv, 64, 64, invn);

  // unary_2: t2b = bf16( leaky(BN(y)) @ W2 ), stats fused (overwrites sort bufs)
  mgemm_k<64, 128, true, true><<<dim3(782, 2), 256, 0, stream>>>(
      ybuf, W2p, t2b, NP, 256, ayv, byv, sum2, sq2);
  finalize_k<<<1, 256, 0, stream>>>(sum2, sq2, g2, b2, a2v, b2v, 256, 32, invn);

  // shortcut: tscb = bf16( x@Wsc ), stats fused (overwrites ybuf/t1b)
  mgemm_k<128, 128, false, true><<<dim3(782, 2), 256, 0, stream>>>(
      x, Wscp, tscb, NP, 256, nullptr, nullptr, sumsc, sqsc);
  finalize_k<<<1, 256, 0, stream>>>(sumsc, sqsc, gsc, bsc, ascv, bscv, 256, 32, invn);

  // out = leaky(BN(t2)) + BN(tsc)
  final_k<<<25000, 256, 0, stream>>>(out, t2b, tscb, a2v, b2v, ascv, bscv);
}